// Round 16
// baseline (1701.682 us; speedup 1.0000x reference)
//
#include <hip/hip_runtime.h>
#include <hip/hip_bf16.h>
#include <math.h>

#define MASK_ID (-100)
#define SEQ 1024
#define BATCH 4
#define DMODEL 768
#define NHEAD 12
#define DHEAD 64
#define NLAYER 10
#define HIDDEN 3072

typedef unsigned short ushort_t;
typedef unsigned int uint_t;

// ---------------------------------------------------------------- bf16 helpers
__device__ __forceinline__ ushort_t f2bf(float f) {
    uint_t u = __float_as_uint(f);
    u = u + 0x7fffu + ((u >> 16) & 1u);   // round-to-nearest-even
    return (ushort_t)(u >> 16);
}
__device__ __forceinline__ float bf2f(ushort_t u) {
    return __uint_as_float(((uint_t)u) << 16);
}

// async global->LDS, 16 bytes per lane
__device__ __forceinline__ void async_ld16(ushort_t* lds, const ushort_t* g) {
    __builtin_amdgcn_global_load_lds((__attribute__((address_space(1))) const void*)g,
                                     (__attribute__((address_space(3))) void*)lds, 16, 0, 0);
}

#define WAITVM(n) asm volatile("s_waitcnt vmcnt(" #n ")" ::: "memory")

// Wt tiled layout: [nb][kb][ni(64)][ki(64)], 4096 bf16 (8 KB) per tile, fully
// contiguous. offset(n,k) = ((nb*KB + kb)<<12) + ni*64 + ki,  KB = K/64.

// ---------------------------------------------------------------- prologue mega-kernel
//   [0, 17280)       : weight transposes -> tiled Wt (10 layers x 1728 tiles)
//   [17280, 17424)   : proj_in_w -> tiled (144 tiles)
//   [17424, 18960)   : x fp32 -> bf16 (1536 blocks)
//   [18960, 19086)   : adaLN e-vectors, SINGLE-STAGE (126 blocks: 6 chunks x 21 slots)
//                      stemb recomputed inline per block (removes temb_silu + reduce)
//   [19086, 19102)   : attention neighbor lists (16 blocks)
#define PREP_GRID 19102
__global__ __launch_bounds__(256)
void prep_all_kernel(const float* __restrict__ w0, const float* __restrict__ w1,
                     const float* __restrict__ w2, const float* __restrict__ w3,
                     ushort_t* __restrict__ o0, ushort_t* __restrict__ o1,
                     ushort_t* __restrict__ o2, ushort_t* __restrict__ o3,
                     const float* __restrict__ proj_in_w, ushort_t* __restrict__ projT,
                     const float* __restrict__ x_in, ushort_t* __restrict__ h_bf,
                     const int* __restrict__ t,
                     const float* __restrict__ a1w, const float* __restrict__ a2w,
                     const float* __restrict__ nw,
                     const float* __restrict__ a1b, const float* __restrict__ a2b,
                     const float* __restrict__ nb_,
                     float* __restrict__ e_all,
                     const int* __restrict__ tok, short* __restrict__ nbr,
                     int* __restrict__ nbr_cnt) {
    __shared__ __align__(16) char smem[4 * DMODEL * 4];   // 12.3 KB (max branch need)
    int gid = blockIdx.x;
    int tid = threadIdx.x;

    if (gid < 17424) {
        // ---- transpose to TILED Wt. W HBM layout: [R=K][C=N] fp32.
        const float* in; ushort_t* out; int R, C, tile_id, TX;
        if (gid < 17280) {
            int layer = gid / 1728;
            int id = gid % 1728;
            if (id < 432) {
                in = w0 + (size_t)layer * DMODEL * 3 * DMODEL; out = o0 + (size_t)layer * 3 * DMODEL * DMODEL;
                R = DMODEL; C = 3 * DMODEL; tile_id = id; TX = 36;
            } else if (id < 576) {
                in = w1 + (size_t)layer * DMODEL * DMODEL; out = o1 + (size_t)layer * DMODEL * DMODEL;
                R = DMODEL; C = DMODEL; tile_id = id - 432; TX = 12;
            } else if (id < 1152) {
                in = w2 + (size_t)layer * DMODEL * HIDDEN; out = o2 + (size_t)layer * HIDDEN * DMODEL;
                R = DMODEL; C = HIDDEN; tile_id = id - 576; TX = 48;
            } else {
                in = w3 + (size_t)layer * HIDDEN * DMODEL; out = o3 + (size_t)layer * DMODEL * HIDDEN;
                R = HIDDEN; C = DMODEL; tile_id = id - 1152; TX = 12;
            }
        } else {
            in = proj_in_w; out = projT; R = DMODEL; C = DMODEL; tile_id = gid - 17280; TX = 12;
        }
        int c0 = (tile_id % TX) * 64, r0 = (tile_id / TX) * 64;   // c = n, r = k
        int KB = R >> 6;
        int nb = c0 >> 6, kb = r0 >> 6;
        ushort_t* tlb = (ushort_t*)smem;   // [r(k)][65]
        #pragma unroll
        for (int i = 0; i < 4; ++i) {
            int idx = i * 256 + tid;
            int r = idx >> 4, c4 = (idx & 15) * 4;
            float4 v = *(const float4*)&in[(size_t)(r0 + r) * C + c0 + c4];
            tlb[r * 65 + c4 + 0] = f2bf(v.x);
            tlb[r * 65 + c4 + 1] = f2bf(v.y);
            tlb[r * 65 + c4 + 2] = f2bf(v.z);
            tlb[r * 65 + c4 + 3] = f2bf(v.w);
        }
        __syncthreads();
        ushort_t* ob = out + (((size_t)(nb * KB + kb)) << 12);
        #pragma unroll
        for (int j = 0; j < 8; ++j) {
            int idx = j * 256 + tid;
            int ni = idx >> 5, kp = idx & 31;
            uint_t pk = (uint_t)tlb[(kp * 2) * 65 + ni] | ((uint_t)tlb[(kp * 2 + 1) * 65 + ni] << 16);
            *(uint_t*)&ob[ni * 64 + kp * 2] = pk;
        }
    } else if (gid < 18960) {
        int i = (gid - 17424) * 256 + tid;
        float4 a = ((const float4*)x_in)[2 * i];
        float4 b = ((const float4*)x_in)[2 * i + 1];
        uint4 o;
        o.x = (uint_t)f2bf(a.x) | ((uint_t)f2bf(a.y) << 16);
        o.y = (uint_t)f2bf(a.z) | ((uint_t)f2bf(a.w) << 16);
        o.z = (uint_t)f2bf(b.x) | ((uint_t)f2bf(b.y) << 16);
        o.w = (uint_t)f2bf(b.z) | ((uint_t)f2bf(b.w) << 16);
        ((uint4*)h_bf)[i] = o;
    } else if (gid < 19086) {
        // ---- adaLN e-vectors, single-stage. Block = (chunk 0..5, slot 0..20).
        int s3 = gid - 18960;
        int chunk = s3 % 6;
        int slot = s3 / 6;
        int col = chunk * 256 + tid;
        const float* W; const float* bb;
        if (slot == 20) { W = nw; bb = nb_; }
        else {
            int i = slot >> 1;
            if (slot & 1) { W = a2w + (size_t)i * DMODEL * 2 * DMODEL; bb = a2b + i * 2 * DMODEL; }
            else          { W = a1w + (size_t)i * DMODEL * 2 * DMODEL; bb = a1b + i * 2 * DMODEL; }
        }
        // inline stemb = silu(timestep_emb(t)): sb[b][j], j<384 sin-part, else cos-part
        float* sb = (float*)smem;    // [4][768]
        for (int idx = tid; idx < 4 * DMODEL; idx += 256) {
            int b = idx / DMODEL, j = idx % DMODEL;
            int jj = (j < 384) ? j : (j - 384);
            float tv = (float)t[b * SEQ];
            float freq = expf(-logf(10000.f) * (float)jj / 383.f);
            float arg = tv * freq;
            float v = (j < 384) ? sinf(arg) : cosf(arg);
            sb[idx] = v / (1.f + expf(-v));
        }
        __syncthreads();
        float bias = bb[col];
        float a0 = bias, a1 = bias, a2 = bias, a3 = bias;
        const float* Wp = W + col;
        #pragma unroll 4
        for (int k = 0; k < DMODEL; ++k) {
            float w = Wp[(size_t)k * (2 * DMODEL)];
            a0 = fmaf(sb[k], w, a0);
            a1 = fmaf(sb[DMODEL + k], w, a1);
            a2 = fmaf(sb[2 * DMODEL + k], w, a2);
            a3 = fmaf(sb[3 * DMODEL + k], w, a3);
        }
        size_t o = (size_t)slot * 4 * (2 * DMODEL) + col;
        e_all[o + 0 * 2 * DMODEL] = a0;
        e_all[o + 1 * 2 * DMODEL] = a1;
        e_all[o + 2 * 2 * DMODEL] = a2;
        e_all[o + 3 * 2 * DMODEL] = a3;
    } else {
        // ---- neighbor lists (order matches original (dh,dw) loop)
        int m = (gid - 19086) * 256 + tid;        // 0..4095
        int b = m >> 10, q = m & 1023;
        int sid = tok[m * 3];
        int cnt = 0;
        short* lst = nbr + (size_t)m * 28;
        if (sid != MASK_ID) {
            int qh = tok[m * 3 + 1], qw = tok[m * 3 + 2];
            for (int dh = -2; dh <= 2; ++dh) {
                for (int dw = -2; dw <= 2; ++dw) {
                    int kq = q + dh * 16 + dw;
                    if (kq < 0 || kq >= SEQ) continue;
                    int km = b * SEQ + kq;
                    if (tok[km * 3] != sid) continue;
                    int kh2 = tok[km * 3 + 1], kw2 = tok[km * 3 + 2];
                    int adh = kh2 - qh; if (adh < 0) adh = -adh;
                    int adw = kw2 - qw; if (adw < 0) adw = -adw;
                    if (adh > 2 || adw > 2) continue;
                    lst[cnt++] = (short)kq;
                }
            }
        }
        nbr_cnt[m] = cnt;
    }
}

// ---------------------------------------------------------------- fused LN + adaLN, wave-per-row
template<int OUT_BF>
__global__ __launch_bounds__(256)
void ln_adaln_kernel(const float* __restrict__ in, void* __restrict__ outv,
                     const float* __restrict__ g, const float* __restrict__ be,
                     const float* __restrict__ e) {
    int wid = threadIdx.x >> 6, lane = threadIdx.x & 63;
    int row = blockIdx.x * 4 + wid;
    int b = row >> 10;
    const float* xr = in + (size_t)row * DMODEL;
    float v[12];
    float s = 0.f, ss = 0.f;
    #pragma unroll
    for (int j = 0; j < 12; ++j) {
        v[j] = xr[lane + j * 64];
        s += v[j];
        ss = fmaf(v[j], v[j], ss);
    }
    #pragma unroll
    for (int o = 1; o < 64; o <<= 1) { s += __shfl_xor(s, o); ss += __shfl_xor(ss, o); }
    float mu = s * (1.f / DMODEL);
    float var = ss * (1.f / DMODEL) - mu * mu;
    float rs = rsqrtf(var + 1e-5f);
    const float* esc = e + (size_t)b * (2 * DMODEL);
    #pragma unroll
    for (int j = 0; j < 12; ++j) {
        int c = lane + j * 64;
        float y = (v[j] - mu) * rs * g[c] + be[c];
        y = y * (1.f + esc[c]) + esc[DMODEL + c];
        if (OUT_BF) ((ushort_t*)outv)[(size_t)row * DMODEL + c] = f2bf(y);
        else        ((float*)outv)[(size_t)row * DMODEL + c] = y;
    }
}

__device__ __forceinline__ float gelu_exact(float x) {
    return 0.5f * x * (1.f + erff(x * 0.70710678118654752f));
}

// ---------------------------------------------------------------- GEMM A: m97-replica, 128x128 tile
// Wt in tiled layout.
template<int EPI>
__global__ __launch_bounds__(256, 3)
void gemm_bf16_big(const ushort_t* __restrict__ A, const ushort_t* __restrict__ Wt,
                   const float* __restrict__ bias, void* __restrict__ outv,
                   int M, int N, int K) {
    constexpr int BM = 128, BN = 128;
    using f32x4  = __attribute__((ext_vector_type(4))) float;
    using bf16x8 = __attribute__((ext_vector_type(8))) short;

    __shared__ __align__(16) ushort_t lds[(BM + BN) * 64];

    int tid = threadIdx.x;
    int lane = tid & 63, wid = tid >> 6;
    int wr = wid >> 1, wc = wid & 1;
    int l16 = lane & 15, lg = lane >> 4;
    int sw = l16 & 7;

    int nx = N / BN;
    int cpx = gridDim.x >> 3;
    int wg = blockIdx.x;
    int wgid = (wg & 7) * cpx + (wg >> 3);
    int bx = wgid % nx, by = wgid / nx;
    int bm0 = by * BM, bn0 = bx * BN;

    f32x4 acc[4][4];
    #pragma unroll
    for (int m = 0; m < 4; ++m)
        #pragma unroll
        for (int n = 0; n < 4; ++n)
            #pragma unroll
            for (int r = 0; r < 4; ++r) acc[m][n][r] = 0.f;

    const ushort_t* Abase = A + (size_t)bm0 * K;
    int KB = K >> 6;
    const ushort_t* Bt0 = Wt + (((size_t)(bn0 >> 6) * KB) << 12);

    int nk = K >> 6;
    for (int kt = 0; kt < nk; ++kt) {
        #pragma unroll
        for (int s2 = 0; s2 < 4; ++s2) {
            int ca = s2 * 256 + tid;
            int rw = ca >> 3, kcs = (ca & 7) ^ (rw & 7);
            async_ld16(&lds[ca * 8], Abase + (size_t)rw * K + kt * 64 + kcs * 8);
        }
        #pragma unroll
        for (int s2 = 0; s2 < 4; ++s2) {
            int ca = s2 * 256 + tid;
            int rw = ca >> 3, kcs = (ca & 7) ^ (rw & 7);
            async_ld16(&lds[BM * 64 + ca * 8],
                       Bt0 + ((((size_t)(rw >> 6) * KB + kt) << 12)) + (rw & 63) * 64 + kcs * 8);
        }
        WAITVM(0);
        __syncthreads();
        #pragma unroll
        for (int kk = 0; kk < 2; ++kk) {
            int csw = (kk * 4 + lg) ^ sw;
            bf16x8 af[4], bfr[4];
            #pragma unroll
            for (int m = 0; m < 4; ++m)
                af[m] = *(const bf16x8*)&lds[(wr * 64 + m * 16 + l16) * 64 + csw * 8];
            #pragma unroll
            for (int n = 0; n < 4; ++n)
                bfr[n] = *(const bf16x8*)&lds[BM * 64 + (wc * 64 + n * 16 + l16) * 64 + csw * 8];
            #pragma unroll
            for (int m = 0; m < 4; ++m)
                #pragma unroll
                for (int n = 0; n < 4; ++n)
                    acc[m][n] = __builtin_amdgcn_mfma_f32_16x16x32_bf16(af[m], bfr[n], acc[m][n], 0, 0, 0);
        }
        __syncthreads();
    }

    int r0 = bm0 + wr * 64, c0 = bn0 + wc * 64;
    #pragma unroll
    for (int m = 0; m < 4; ++m) {
        #pragma unroll
        for (int n = 0; n < 4; ++n) {
            int cc = c0 + n * 16 + l16;
            float bcol = bias[cc];
            #pragma unroll
            for (int r = 0; r < 4; ++r) {
                int row = r0 + m * 16 + lg * 4 + r;
                float v = acc[m][n][r] + bcol;
                if (EPI == 0) ((ushort_t*)outv)[(size_t)row * N + cc] = f2bf(v);
                else          ((ushort_t*)outv)[(size_t)row * N + cc] = f2bf(gelu_exact(v));
            }
        }
    }
}

// ---------------------------------------------------------------- GEMM B: v3 3-buffer counted-vmcnt
// Wt in tiled layout.
template<int BM, int BN, int EPI, int OCC>
__global__ __launch_bounds__(256, OCC)
void gemm_bf16(const ushort_t* __restrict__ A, const ushort_t* __restrict__ Wt,
               const float* __restrict__ bias, void* __restrict__ outv,
               const float* __restrict__ emb_h, const float* __restrict__ emb_w,
               const int* __restrict__ tok,
               int M, int N, int K) {
    constexpr int WM = BM / 2, WN = BN / 2;
    constexpr int FM = WM / 16, FN = WN / 16;
    constexpr int BUF = (BM + BN) * 64;
    constexpr int LPT = (BM + BN) / 32;
    using f32x4  = __attribute__((ext_vector_type(4))) float;
    using bf16x8 = __attribute__((ext_vector_type(8))) short;

    __shared__ __align__(16) ushort_t lds[3 * BUF];

    int tid = threadIdx.x;
    int lane = tid & 63, wid = tid >> 6;
    int wr = wid >> 1, wc = wid & 1;
    int l16 = lane & 15, lg = lane >> 4;
    int sw = l16 & 7;

    int nx = N / BN;
    int cpx = gridDim.x >> 3;
    int wg = blockIdx.x;
    int wgid = (wg & 7) * cpx + (wg >> 3);
    int bx = wgid % nx, by = wgid / nx;
    int bm0 = by * BM, bn0 = bx * BN;

    f32x4 acc[FM][FN];
    #pragma unroll
    for (int m = 0; m < FM; ++m)
        #pragma unroll
        for (int n = 0; n < FN; ++n)
            #pragma unroll
            for (int r = 0; r < 4; ++r) acc[m][n][r] = 0.f;

    const ushort_t* Abase = A + (size_t)bm0 * K;
    int KB = K >> 6;
    const ushort_t* Bt0 = Wt + (((size_t)(bn0 >> 6) * KB) << 12);

    #define STAGE(bufi, kt)                                                             \
        do {                                                                            \
            _Pragma("unroll")                                                           \
            for (int s2 = 0; s2 < BM / 32; ++s2) {                                      \
                int ca = s2 * 256 + tid;                                                \
                int rw = ca >> 3, kcs = (ca & 7) ^ (rw & 7);                            \
                async_ld16(&lds[(bufi) * BUF + ca * 8],                                 \
                           Abase + (size_t)rw * K + (kt) * 64 + kcs * 8);               \
            }                                                                           \
            _Pragma("unroll")                                                           \
            for (int s2 = 0; s2 < BN / 32; ++s2) {                                      \
                int ca = s2 * 256 + tid;                                                \
                int rw = ca >> 3, kcs = (ca & 7) ^ (rw & 7);                            \
                async_ld16(&lds[(bufi) * BUF + BM * 64 + ca * 8],                       \
                           Bt0 + ((((size_t)(rw >> 6) * KB + (kt)) << 12))              \
                               + (rw & 63) * 64 + kcs * 8);                             \
            }                                                                           \
        } while (0)

    int nk = K >> 6;
    STAGE(0, 0);
    STAGE(1, 1);
    int bufi = 0;
    for (int kt = 0; kt < nk; ++kt) {
        int nxt = bufi + 2; if (nxt >= 3) nxt -= 3;
        if (kt + 2 < nk) {
            STAGE(nxt, kt + 2);
            if constexpr (LPT == 4) WAITVM(8); else WAITVM(12);
        } else if (kt + 1 < nk) {
            if constexpr (LPT == 4) WAITVM(4); else WAITVM(6);
        } else {
            WAITVM(0);
        }
        __builtin_amdgcn_s_barrier();
        __builtin_amdgcn_s_setprio(1);
        #pragma unroll
        for (int kk = 0; kk < 2; ++kk) {
            bf16x8 af[FM], bfr[FN];
            #pragma unroll
            for (int m = 0; m < FM; ++m) {
                int row = wr * WM + m * 16 + l16;
                int csw = (kk * 4 + lg) ^ sw;
                af[m] = *(const bf16x8*)&lds[bufi * BUF + row * 64 + csw * 8];
            }
            #pragma unroll
            for (int n = 0; n < FN; ++n) {
                int row = wc * WN + n * 16 + l16;
                int csw = (kk * 4 + lg) ^ sw;
                bfr[n] = *(const bf16x8*)&lds[bufi * BUF + BM * 64 + row * 64 + csw * 8];
            }
            #pragma unroll
            for (int m = 0; m < FM; ++m)
                #pragma unroll
                for (int n = 0; n < FN; ++n)
                    acc[m][n] = __builtin_amdgcn_mfma_f32_16x16x32_bf16(af[m], bfr[n], acc[m][n], 0, 0, 0);
        }
        __builtin_amdgcn_s_setprio(0);
        __builtin_amdgcn_s_barrier();
        ++bufi; if (bufi >= 3) bufi = 0;
    }
    #undef STAGE

    int r0 = bm0 + wr * WM, c0 = bn0 + wc * WN;
    #pragma unroll
    for (int m = 0; m < FM; ++m) {
        #pragma unroll
        for (int n = 0; n < FN; ++n) {
            int cc = c0 + n * 16 + l16;
            float bcol = bias[cc];
            #pragma unroll
            for (int r = 0; r < 4; ++r) {
                int row = r0 + m * 16 + lg * 4 + r;
                float v = acc[m][n][r] + bcol;
                if (EPI == 0) {
                    ((ushort_t*)outv)[(size_t)row * N + cc] = f2bf(v);
                } else if (EPI == 1) {
                    int p0 = tok[row * 3 + 1], p1 = tok[row * 3 + 2];
                    v += emb_h[p0 * DMODEL + cc] + emb_w[p1 * DMODEL + cc];
                    ((float*)outv)[(size_t)row * N + cc] = v;
                } else if (EPI == 2) {
                    float* op = (float*)outv + (size_t)row * N + cc;
                    *op = *op + v;
                } else {
                    ((ushort_t*)outv)[(size_t)row * N + cc] = f2bf(gelu_exact(v));
                }
            }
        }
    }
}

// ---------------------------------------------------------------- sparse local attention (list-driven)
__global__ __launch_bounds__(256)
void attn_kernel(const ushort_t* __restrict__ qkv, const short* __restrict__ nbr,
                 const int* __restrict__ nbr_cnt, ushort_t* __restrict__ o_out) {
    int tid = threadIdx.x;
    int u = tid >> 2, part = tid & 3;
    int q = blockIdx.x * 16 + (u & 15);
    int h = blockIdx.y * 4 + (u >> 4);
    int b = blockIdx.z;
    int m = b * SEQ + q;
    ushort_t* op = o_out + (size_t)m * DMODEL + h * DHEAD + part * 16;
    int cnt = nbr_cnt[m];
    if (cnt == 0) {
        uint4 z = {0u, 0u, 0u, 0u};
        ((uint4*)op)[0] = z;
        ((uint4*)op)[1] = z;
        return;
    }
    const short* lst = nbr + (size_t)m * 28;
    const ushort_t* qp = qkv + (size_t)m * (3 * DMODEL) + h * DHEAD + part * 16;
    float qv[16], ov[16];
    {
        uint4 u0 = ((const uint4*)qp)[0];
        uint4 u1 = ((const uint4*)qp)[1];
        qv[0] = bf2f(u0.x & 0xffff) * 0.125f; qv[1] = bf2f(u0.x >> 16) * 0.125f;
        qv[2] = bf2f(u0.y & 0xffff) * 0.125f; qv[3] = bf2f(u0.y >> 16) * 0.125f;
        qv[4] = bf2f(u0.z & 0xffff) * 0.125f; qv[5] = bf2f(u0.z >> 16) * 0.125f;
        qv[6] = bf2f(u0.w & 0xffff) * 0.125f; qv[7] = bf2f(u0.w >> 16) * 0.125f;
        qv[8]  = bf2f(u1.x & 0xffff) * 0.125f; qv[9]  = bf2f(u1.x >> 16) * 0.125f;
        qv[10] = bf2f(u1.y & 0xffff) * 0.125f; qv[11] = bf2f(u1.y >> 16) * 0.125f;
        qv[12] = bf2f(u1.z & 0xffff) * 0.125f; qv[13] = bf2f(u1.z >> 16) * 0.125f;
        qv[14] = bf2f(u1.w & 0xffff) * 0.125f; qv[15] = bf2f(u1.w >> 16) * 0.125f;
    }
    #pragma unroll
    for (int i = 0; i < 16; ++i) ov[i] = 0.f;
    float mx = -1e30f, den = 0.f;
    for (int it = 0; it < cnt; ++it) {
        int km = b * SEQ + (int)lst[it];
        const ushort_t* kp = qkv + (size_t)km * (3 * DMODEL) + DMODEL + h * DHEAD + part * 16;
        float dot;
        {
            uint4 u0 = ((const uint4*)kp)[0];
            uint4 u1 = ((const uint4*)kp)[1];
            dot = qv[0] * bf2f(u0.x & 0xffff);
            dot = fmaf(qv[1], bf2f(u0.x >> 16), dot);
            dot = fmaf(qv[2], bf2f(u0.y & 0xffff), dot);
            dot = fmaf(qv[3], bf2f(u0.y >> 16), dot);
            dot = fmaf(qv[4], bf2f(u0.z & 0xffff), dot);
            dot = fmaf(qv[5], bf2f(u0.z >> 16), dot);
            dot = fmaf(qv[6], bf2f(u0.w & 0xffff), dot);
            dot = fmaf(qv[7], bf2f(u0.w >> 16), dot);
            dot = fmaf(qv[8],  bf2f(u1.x & 0xffff), dot);
            dot = fmaf(qv[9],  bf2f(u1.x >> 16), dot);
            dot = fmaf(qv[10], bf2f(u1.y & 0xffff), dot);
            dot = fmaf(qv[11], bf2f(u1.y >> 16), dot);
            dot = fmaf(qv[12], bf2f(u1.z & 0xffff), dot);
            dot = fmaf(qv[13], bf2f(u1.z >> 16), dot);
            dot = fmaf(qv[14], bf2f(u1.w & 0xffff), dot);
            dot = fmaf(qv[15], bf2f(u1.w >> 16), dot);
        }
        dot += __shfl_xor(dot, 1);
        dot += __shfl_xor(dot, 2);
        float sc = dot;
        float nm = fmaxf(mx, sc);
        float c1 = expf(mx - nm);
        float c2 = expf(sc - nm);
        den = den * c1 + c2;
        const ushort_t* vp = qkv + (size_t)km * (3 * DMODEL) + 2 * DMODEL + h * DHEAD + part * 16;
        {
            uint4 u0 = ((const uint4*)vp)[0];
            uint4 u1 = ((const uint4*)vp)[1];
            ov[0] = ov[0] * c1 + c2 * bf2f(u0.x & 0xffff);
            ov[1] = ov[1] * c1 + c2 * bf2f(u0.x >> 16);
            ov[2] = ov[2] * c1 + c2 * bf2f(u0.y & 0xffff);
            ov[3] = ov[3] * c1 + c2 * bf2f(u0.y >> 16);
            ov[4] = ov[4] * c1 + c2 * bf2f(u0.z & 0xffff);
            ov[5] = ov[5] * c1 + c2 * bf2f(u0.z >> 16);
            ov[6] = ov[6] * c1 + c2 * bf2f(u0.w & 0xffff);
            ov[7] = ov[7] * c1 + c2 * bf2f(u0.w >> 16);
            ov[8]  = ov[8]  * c1 + c2 * bf2f(u1.x & 0xffff);
            ov[9]  = ov[9]  * c1 + c2 * bf2f(u1.x >> 16);
            ov[10] = ov[10] * c1 + c2 * bf2f(u1.y & 0xffff);
            ov[11] = ov[11] * c1 + c2 * bf2f(u1.y >> 16);
            ov[12] = ov[12] * c1 + c2 * bf2f(u1.z & 0xffff);
            ov[13] = ov[13] * c1 + c2 * bf2f(u1.z >> 16);
            ov[14] = ov[14] * c1 + c2 * bf2f(u1.w & 0xffff);
            ov[15] = ov[15] * c1 + c2 * bf2f(u1.w >> 16);
        }
        mx = nm;
    }
    float inv = 1.f / den;
    uint4 o0, o1;
    o0.x = (uint_t)f2bf(ov[0] * inv) | ((uint_t)f2bf(ov[1] * inv) << 16);
    o0.y = (uint_t)f2bf(ov[2] * inv) | ((uint_t)f2bf(ov[3] * inv) << 16);
    o0.z = (uint_t)f2bf(ov[4] * inv) | ((uint_t)f2bf(ov[5] * inv) << 16);
    o0.w = (uint_t)f2bf(ov[6] * inv) | ((uint_t)f2bf(ov[7] * inv) << 16);
    o1.x = (uint_t)f2bf(ov[8]  * inv) | ((uint_t)f2bf(ov[9]  * inv) << 16);
    o1.y = (uint_t)f2bf(ov[10] * inv) | ((uint_t)f2bf(ov[11] * inv) << 16);
    o1.z = (uint_t)f2bf(ov[12] * inv) | ((uint_t)f2bf(ov[13] * inv) << 16);
    o1.w = (uint_t)f2bf(ov[14] * inv) | ((uint_t)f2bf(ov[15] * inv) << 16);
    ((uint4*)op)[0] = o0;
    ((uint4*)op)[1] = o1;
}

// ---------------------------------------------------------------- launch
extern "C" void kernel_launch(void* const* d_in, const int* in_sizes, int n_in,
                              void* d_out, int out_size, void* d_ws, size_t ws_size,
                              hipStream_t stream) {
    const float* x_in      = (const float*)d_in[0];
    const int*   t         = (const int*)d_in[1];
    const int*   tok       = (const int*)d_in[2];
    const float* proj_in_w = (const float*)d_in[3];
    const float* proj_in_b = (const float*)d_in[4];
    const float* h_emb     = (const float*)d_in[5];
    const float* w_emb     = (const float*)d_in[6];
    const float* adaln1_w  = (const float*)d_in[7];
    const float* adaln1_b  = (const float*)d_in[8];
    const float* ln1_g     = (const float*)d_in[9];
    const float* ln1_b     = (const float*)d_in[10];
    const float* qkv_w     = (const float*)d_in[11];
    const float* qkv_b     = (const float*)d_in[12];
    const float* o_w       = (const float*)d_in[13];
    const float* o_b       = (const float*)d_in[14];
    const float* adaln2_w  = (const float*)d_in[15];
    const float* adaln2_b  = (const float*)d_in[16];
    const float* ln2_g     = (const float*)d_in[17];
    const float* ln2_b     = (const float*)d_in[18];
    const float* fc1_w     = (const float*)d_in[19];
    const float* fc1_b     = (const float*)d_in[20];
    const float* fc2_w     = (const float*)d_in[21];
    const float* fc2_b     = (const float*)d_in[22];
    const float* nout_w    = (const float*)d_in[23];
    const float* nout_b    = (const float*)d_in[24];
    const float* nout_g    = (const float*)d_in[25];
    const float* nout_beta = (const float*)d_in[26];

    const int M = BATCH * SEQ;   // 4096

    float* e_all   = (float*)d_ws;                          // 21*4*1536
    int*   nbr_cnt = (int*)(e_all + 21 * BATCH * 2 * DMODEL);
    short* nbr     = (short*)(nbr_cnt + M);
    ushort_t* h_bf   = (ushort_t*)(nbr + (size_t)M * 28);
    ushort_t* qkv_bf = h_bf + (size_t)M * DMODEL;
    ushort_t* hid_bf = qkv_bf + (size_t)M * 3 * DMODEL;
    ushort_t* projT  = hid_bf + (size_t)M * HIDDEN;
    ushort_t* qkvT_a = projT + (size_t)DMODEL * DMODEL;     // 10 layers
    ushort_t* oT_a   = qkvT_a + (size_t)NLAYER * 3 * DMODEL * DMODEL;
    ushort_t* fc1T_a = oT_a + (size_t)NLAYER * DMODEL * DMODEL;
    ushort_t* fc2T_a = fc1T_a + (size_t)NLAYER * DMODEL * HIDDEN;
    float* x = (float*)d_out;

    prep_all_kernel<<<PREP_GRID, 256, 0, stream>>>(
        qkv_w, o_w, fc1_w, fc2_w, qkvT_a, oT_a, fc1T_a, fc2T_a,
        proj_in_w, projT, x_in, h_bf, t, adaln1_w, adaln2_w, nout_w,
        adaln1_b, adaln2_b, nout_b, e_all, tok, nbr, nbr_cnt);

    // proj_in: v3 64x64, 768 blocks
    gemm_bf16<64, 64, 1, 3><<<(DMODEL / 64) * (M / 64), 256, 0, stream>>>(
        h_bf, projT, proj_in_b, x, h_emb, w_emb, tok, M, DMODEL, DMODEL);

    for (int i = 0; i < NLAYER; ++i) {
        ln_adaln_kernel<1><<<M / 4, 256, 0, stream>>>(
            x, h_bf, ln1_g + i * DMODEL, ln1_b + i * DMODEL,
            e_all + (size_t)(2 * i) * BATCH * 2 * DMODEL);
        // qkv: 128x128 replica, 576 blocks
        gemm_bf16_big<0><<<(3 * DMODEL / 128) * (M / 128), 256, 0, stream>>>(
            h_bf, qkvT_a + (size_t)i * 3 * DMODEL * DMODEL, qkv_b + i * 3 * DMODEL,
            qkv_bf, M, 3 * DMODEL, DMODEL);
        attn_kernel<<<dim3(SEQ / 16, NHEAD / 4, BATCH), 256, 0, stream>>>(qkv_bf, nbr, nbr_cnt, h_bf);
        // o-proj: v3 64x64, 768 blocks (residual)
        gemm_bf16<64, 64, 2, 3><<<(DMODEL / 64) * (M / 64), 256, 0, stream>>>(
            h_bf, oT_a + (size_t)i * DMODEL * DMODEL, o_b + i * DMODEL,
            x, nullptr, nullptr, nullptr, M, DMODEL, DMODEL);
        ln_adaln_kernel<1><<<M / 4, 256, 0, stream>>>(
            x, h_bf, ln2_g + i * DMODEL, ln2_b + i * DMODEL,
            e_all + (size_t)(2 * i + 1) * BATCH * 2 * DMODEL);
        // fc1: 128x128 replica + gelu, 768 blocks
        gemm_bf16_big<3><<<(HIDDEN / 128) * (M / 128), 256, 0, stream>>>(
            h_bf, fc1T_a + (size_t)i * DMODEL * HIDDEN, fc1_b + i * HIDDEN,
            hid_bf, M, HIDDEN, DMODEL);
        // fc2: v3 pipelined 128x64, 384 blocks (K=3072: 48-step pipeline)
        gemm_bf16<128, 64, 2, 2><<<(DMODEL / 64) * (M / 128), 256, 0, stream>>>(
            hid_bf, fc2T_a + (size_t)i * DMODEL * HIDDEN, fc2_b + i * DMODEL,
            x, nullptr, nullptr, nullptr, M, DMODEL, HIDDEN);
    }

    ln_adaln_kernel<0><<<M / 4, 256, 0, stream>>>(
        x, x, nout_g, nout_beta, e_all + (size_t)(2 * NLAYER) * BATCH * 2 * DMODEL);
}

// Round 17
// 1619.471 us; speedup vs baseline: 1.0508x; 1.0508x over previous
//
#include <hip/hip_runtime.h>
#include <hip/hip_bf16.h>
#include <math.h>

#define MASK_ID (-100)
#define SEQ 1024
#define BATCH 4
#define DMODEL 768
#define NHEAD 12
#define DHEAD 64
#define NLAYER 10
#define HIDDEN 3072

typedef unsigned short ushort_t;
typedef unsigned int uint_t;

// ---------------------------------------------------------------- bf16 helpers
__device__ __forceinline__ ushort_t f2bf(float f) {
    uint_t u = __float_as_uint(f);
    u = u + 0x7fffu + ((u >> 16) & 1u);   // round-to-nearest-even
    return (ushort_t)(u >> 16);
}
__device__ __forceinline__ float bf2f(ushort_t u) {
    return __uint_as_float(((uint_t)u) << 16);
}

// async global->LDS, 16 bytes per lane
__device__ __forceinline__ void async_ld16(ushort_t* lds, const ushort_t* g) {
    __builtin_amdgcn_global_load_lds((__attribute__((address_space(1))) const void*)g,
                                     (__attribute__((address_space(3))) void*)lds, 16, 0, 0);
}

#define WAITVM(n) asm volatile("s_waitcnt vmcnt(" #n ")" ::: "memory")

// Wt tiled layout: [nb][kb][ni(64)][ki(64)], 4096 bf16 (8 KB) per tile, fully
// contiguous. offset(n,k) = ((nb*KB + kb)<<12) + ni*64 + ki,  KB = K/64.

// ---------------------------------------------------------------- temb+silu
__global__ void temb_silu_kernel(const int* __restrict__ t, float* __restrict__ stemb) {
    int b = blockIdx.x;
    int j = threadIdx.x;           // 0..383
    float tv = (float)t[b * SEQ];
    float freq = expf(-logf(10000.f) * (float)j / 383.f);
    float arg = tv * freq;
    float s = sinf(arg), c = cosf(arg);
    stemb[b * DMODEL + j]       = s / (1.f + expf(-s));
    stemb[b * DMODEL + 384 + j] = c / (1.f + expf(-c));
}

// ---------------------------------------------------------------- prologue mega-kernel
//   [0, 17280)       : weight transposes -> tiled Wt (10 layers x 1728 tiles)
//   [17280, 17424)   : proj_in_w -> tiled (144 tiles)
//   [17424, 18960)   : x fp32 -> bf16 (1536 blocks)
//   [18960, 19968)   : adaln stage-1 partials (1008)
//   [19968, 19984)   : attention neighbor lists (16 blocks)
#define PREP_GRID 19984
__global__ __launch_bounds__(256)
void prep_all_kernel(const float* __restrict__ w0, const float* __restrict__ w1,
                     const float* __restrict__ w2, const float* __restrict__ w3,
                     ushort_t* __restrict__ o0, ushort_t* __restrict__ o1,
                     ushort_t* __restrict__ o2, ushort_t* __restrict__ o3,
                     const float* __restrict__ proj_in_w, ushort_t* __restrict__ projT,
                     const float* __restrict__ x_in, ushort_t* __restrict__ h_bf,
                     const float* __restrict__ stemb,
                     const float* __restrict__ a1w, const float* __restrict__ a2w,
                     const float* __restrict__ nw, float* __restrict__ partial,
                     const int* __restrict__ tok, short* __restrict__ nbr,
                     int* __restrict__ nbr_cnt) {
    __shared__ __align__(16) char smem[64 * 65 * 2];
    int gid = blockIdx.x;
    int tid = threadIdx.x;

    if (gid < 17424) {
        // ---- transpose to TILED Wt. W HBM layout: [R=K][C=N] fp32.
        const float* in; ushort_t* out; int R, C, tile_id, TX;
        if (gid < 17280) {
            int layer = gid / 1728;
            int id = gid % 1728;
            if (id < 432) {
                in = w0 + (size_t)layer * DMODEL * 3 * DMODEL; out = o0 + (size_t)layer * 3 * DMODEL * DMODEL;
                R = DMODEL; C = 3 * DMODEL; tile_id = id; TX = 36;
            } else if (id < 576) {
                in = w1 + (size_t)layer * DMODEL * DMODEL; out = o1 + (size_t)layer * DMODEL * DMODEL;
                R = DMODEL; C = DMODEL; tile_id = id - 432; TX = 12;
            } else if (id < 1152) {
                in = w2 + (size_t)layer * DMODEL * HIDDEN; out = o2 + (size_t)layer * HIDDEN * DMODEL;
                R = DMODEL; C = HIDDEN; tile_id = id - 576; TX = 48;
            } else {
                in = w3 + (size_t)layer * HIDDEN * DMODEL; out = o3 + (size_t)layer * DMODEL * HIDDEN;
                R = HIDDEN; C = DMODEL; tile_id = id - 1152; TX = 12;
            }
        } else {
            in = proj_in_w; out = projT; R = DMODEL; C = DMODEL; tile_id = gid - 17280; TX = 12;
        }
        int c0 = (tile_id % TX) * 64, r0 = (tile_id / TX) * 64;   // c = n, r = k
        int KB = R >> 6;
        int nb = c0 >> 6, kb = r0 >> 6;
        ushort_t* tlb = (ushort_t*)smem;   // [r(k)][65]
        #pragma unroll
        for (int i = 0; i < 4; ++i) {
            int idx = i * 256 + tid;
            int r = idx >> 4, c4 = (idx & 15) * 4;
            float4 v = *(const float4*)&in[(size_t)(r0 + r) * C + c0 + c4];
            tlb[r * 65 + c4 + 0] = f2bf(v.x);
            tlb[r * 65 + c4 + 1] = f2bf(v.y);
            tlb[r * 65 + c4 + 2] = f2bf(v.z);
            tlb[r * 65 + c4 + 3] = f2bf(v.w);
        }
        __syncthreads();
        ushort_t* ob = out + (((size_t)(nb * KB + kb)) << 12);
        #pragma unroll
        for (int j = 0; j < 8; ++j) {
            int idx = j * 256 + tid;
            int ni = idx >> 5, kp = idx & 31;
            uint_t pk = (uint_t)tlb[(kp * 2) * 65 + ni] | ((uint_t)tlb[(kp * 2 + 1) * 65 + ni] << 16);
            *(uint_t*)&ob[ni * 64 + kp * 2] = pk;
        }
    } else if (gid < 18960) {
        int i = (gid - 17424) * 256 + tid;
        float4 a = ((const float4*)x_in)[2 * i];
        float4 b = ((const float4*)x_in)[2 * i + 1];
        uint4 o;
        o.x = (uint_t)f2bf(a.x) | ((uint_t)f2bf(a.y) << 16);
        o.y = (uint_t)f2bf(a.z) | ((uint_t)f2bf(a.w) << 16);
        o.z = (uint_t)f2bf(b.x) | ((uint_t)f2bf(b.y) << 16);
        o.w = (uint_t)f2bf(b.z) | ((uint_t)f2bf(b.w) << 16);
        ((uint4*)h_bf)[i] = o;
    } else if (gid < 19968) {
        int s3 = gid - 18960;
        int chunk = s3 % 6;
        int kc = (s3 / 6) % 8;
        int slot = s3 / 48;
        int col = chunk * 256 + tid;
        const float* W;
        if (slot == 20) W = nw;
        else {
            int i = slot >> 1;
            W = ((slot & 1) ? a2w : a1w) + (size_t)i * DMODEL * 2 * DMODEL;
        }
        float* sb = (float*)smem;
        for (int idx = tid; idx < 4 * 96; idx += 256) {
            int bb = idx / 96, kk = idx % 96;
            sb[idx] = stemb[bb * DMODEL + kc * 96 + kk];
        }
        __syncthreads();
        const float* Wp = W + (size_t)(kc * 96) * (2 * DMODEL) + col;
        float a0 = 0.f, a1 = 0.f, a2 = 0.f, a3 = 0.f;
        #pragma unroll 4
        for (int kk = 0; kk < 96; ++kk) {
            float w = Wp[(size_t)kk * (2 * DMODEL)];
            a0 = fmaf(sb[kk], w, a0);
            a1 = fmaf(sb[96 + kk], w, a1);
            a2 = fmaf(sb[192 + kk], w, a2);
            a3 = fmaf(sb[288 + kk], w, a3);
        }
        size_t base = ((size_t)(slot * 8 + kc) * 4) * (2 * DMODEL) + col;
        partial[base + 0 * 2 * DMODEL] = a0;
        partial[base + 1 * 2 * DMODEL] = a1;
        partial[base + 2 * 2 * DMODEL] = a2;
        partial[base + 3 * 2 * DMODEL] = a3;
    } else {
        // ---- neighbor lists (order matches original (dh,dw) loop)
        int m = (gid - 19968) * 256 + tid;        // 0..4095
        int b = m >> 10, q = m & 1023;
        int sid = tok[m * 3];
        int cnt = 0;
        short* lst = nbr + (size_t)m * 28;
        if (sid != MASK_ID) {
            int qh = tok[m * 3 + 1], qw = tok[m * 3 + 2];
            for (int dh = -2; dh <= 2; ++dh) {
                for (int dw = -2; dw <= 2; ++dw) {
                    int kq = q + dh * 16 + dw;
                    if (kq < 0 || kq >= SEQ) continue;
                    int km = b * SEQ + kq;
                    if (tok[km * 3] != sid) continue;
                    int kh2 = tok[km * 3 + 1], kw2 = tok[km * 3 + 2];
                    int adh = kh2 - qh; if (adh < 0) adh = -adh;
                    int adw = kw2 - qw; if (adw < 0) adw = -adw;
                    if (adh > 2 || adw > 2) continue;
                    lst[cnt++] = (short)kq;
                }
            }
        }
        nbr_cnt[m] = cnt;
    }
}

__global__ __launch_bounds__(256)
void adaln_reduce_kernel(const float* __restrict__ partial,
                         const float* __restrict__ a1b, const float* __restrict__ a2b,
                         const float* __restrict__ nb,
                         float* __restrict__ e_all) {
    int chunk = blockIdx.x;   // 0..5
    int slot  = blockIdx.y;   // 0..20
    int col = chunk * 256 + threadIdx.x;
    const float* bb;
    if (slot == 20) bb = nb;
    else {
        int i = slot >> 1;
        bb = ((slot & 1) ? a2b : a1b) + i * 2 * DMODEL;
    }
    float bias = bb[col];
    float s0 = bias, s1 = bias, s2 = bias, s3 = bias;
    #pragma unroll
    for (int kc = 0; kc < 8; ++kc) {
        size_t base = ((size_t)(slot * 8 + kc) * 4) * (2 * DMODEL) + col;
        s0 += partial[base + 0 * 2 * DMODEL];
        s1 += partial[base + 1 * 2 * DMODEL];
        s2 += partial[base + 2 * 2 * DMODEL];
        s3 += partial[base + 3 * 2 * DMODEL];
    }
    size_t o = (size_t)slot * 4 * (2 * DMODEL) + col;
    e_all[o + 0 * 2 * DMODEL] = s0;
    e_all[o + 1 * 2 * DMODEL] = s1;
    e_all[o + 2 * 2 * DMODEL] = s2;
    e_all[o + 3 * 2 * DMODEL] = s3;
}

// ---------------------------------------------------------------- fused LN + adaLN, wave-per-row
template<int OUT_BF>
__global__ __launch_bounds__(256)
void ln_adaln_kernel(const float* __restrict__ in, void* __restrict__ outv,
                     const float* __restrict__ g, const float* __restrict__ be,
                     const float* __restrict__ e) {
    int wid = threadIdx.x >> 6, lane = threadIdx.x & 63;
    int row = blockIdx.x * 4 + wid;
    int b = row >> 10;
    const float* xr = in + (size_t)row * DMODEL;
    float v[12];
    float s = 0.f, ss = 0.f;
    #pragma unroll
    for (int j = 0; j < 12; ++j) {
        v[j] = xr[lane + j * 64];
        s += v[j];
        ss = fmaf(v[j], v[j], ss);
    }
    #pragma unroll
    for (int o = 1; o < 64; o <<= 1) { s += __shfl_xor(s, o); ss += __shfl_xor(ss, o); }
    float mu = s * (1.f / DMODEL);
    float var = ss * (1.f / DMODEL) - mu * mu;
    float rs = rsqrtf(var + 1e-5f);
    const float* esc = e + (size_t)b * (2 * DMODEL);
    #pragma unroll
    for (int j = 0; j < 12; ++j) {
        int c = lane + j * 64;
        float y = (v[j] - mu) * rs * g[c] + be[c];
        y = y * (1.f + esc[c]) + esc[DMODEL + c];
        if (OUT_BF) ((ushort_t*)outv)[(size_t)row * DMODEL + c] = f2bf(y);
        else        ((float*)outv)[(size_t)row * DMODEL + c] = y;
    }
}

__device__ __forceinline__ float gelu_exact(float x) {
    return 0.5f * x * (1.f + erff(x * 0.70710678118654752f));
}

// ---------------------------------------------------------------- GEMM A: m97-replica, 128x128 tile
// Wt in tiled layout.
template<int EPI>
__global__ __launch_bounds__(256, 3)
void gemm_bf16_big(const ushort_t* __restrict__ A, const ushort_t* __restrict__ Wt,
                   const float* __restrict__ bias, void* __restrict__ outv,
                   int M, int N, int K) {
    constexpr int BM = 128, BN = 128;
    using f32x4  = __attribute__((ext_vector_type(4))) float;
    using bf16x8 = __attribute__((ext_vector_type(8))) short;

    __shared__ __align__(16) ushort_t lds[(BM + BN) * 64];

    int tid = threadIdx.x;
    int lane = tid & 63, wid = tid >> 6;
    int wr = wid >> 1, wc = wid & 1;
    int l16 = lane & 15, lg = lane >> 4;
    int sw = l16 & 7;

    int nx = N / BN;
    int cpx = gridDim.x >> 3;
    int wg = blockIdx.x;
    int wgid = (wg & 7) * cpx + (wg >> 3);
    int bx = wgid % nx, by = wgid / nx;
    int bm0 = by * BM, bn0 = bx * BN;

    f32x4 acc[4][4];
    #pragma unroll
    for (int m = 0; m < 4; ++m)
        #pragma unroll
        for (int n = 0; n < 4; ++n)
            #pragma unroll
            for (int r = 0; r < 4; ++r) acc[m][n][r] = 0.f;

    const ushort_t* Abase = A + (size_t)bm0 * K;
    int KB = K >> 6;
    const ushort_t* Bt0 = Wt + (((size_t)(bn0 >> 6) * KB) << 12);

    int nk = K >> 6;
    for (int kt = 0; kt < nk; ++kt) {
        #pragma unroll
        for (int s2 = 0; s2 < 4; ++s2) {
            int ca = s2 * 256 + tid;
            int rw = ca >> 3, kcs = (ca & 7) ^ (rw & 7);
            async_ld16(&lds[ca * 8], Abase + (size_t)rw * K + kt * 64 + kcs * 8);
        }
        #pragma unroll
        for (int s2 = 0; s2 < 4; ++s2) {
            int ca = s2 * 256 + tid;
            int rw = ca >> 3, kcs = (ca & 7) ^ (rw & 7);
            async_ld16(&lds[BM * 64 + ca * 8],
                       Bt0 + ((((size_t)(rw >> 6) * KB + kt) << 12)) + (rw & 63) * 64 + kcs * 8);
        }
        WAITVM(0);
        __syncthreads();
        #pragma unroll
        for (int kk = 0; kk < 2; ++kk) {
            int csw = (kk * 4 + lg) ^ sw;
            bf16x8 af[4], bfr[4];
            #pragma unroll
            for (int m = 0; m < 4; ++m)
                af[m] = *(const bf16x8*)&lds[(wr * 64 + m * 16 + l16) * 64 + csw * 8];
            #pragma unroll
            for (int n = 0; n < 4; ++n)
                bfr[n] = *(const bf16x8*)&lds[BM * 64 + (wc * 64 + n * 16 + l16) * 64 + csw * 8];
            #pragma unroll
            for (int m = 0; m < 4; ++m)
                #pragma unroll
                for (int n = 0; n < 4; ++n)
                    acc[m][n] = __builtin_amdgcn_mfma_f32_16x16x32_bf16(af[m], bfr[n], acc[m][n], 0, 0, 0);
        }
        __syncthreads();
    }

    int r0 = bm0 + wr * 64, c0 = bn0 + wc * 64;
    #pragma unroll
    for (int m = 0; m < 4; ++m) {
        #pragma unroll
        for (int n = 0; n < 4; ++n) {
            int cc = c0 + n * 16 + l16;
            float bcol = bias[cc];
            #pragma unroll
            for (int r = 0; r < 4; ++r) {
                int row = r0 + m * 16 + lg * 4 + r;
                float v = acc[m][n][r] + bcol;
                if (EPI == 0) ((ushort_t*)outv)[(size_t)row * N + cc] = f2bf(v);
                else          ((ushort_t*)outv)[(size_t)row * N + cc] = f2bf(gelu_exact(v));
            }
        }
    }
}

// ---------------------------------------------------------------- GEMM B: v3 3-buffer counted-vmcnt
// Wt in tiled layout.
template<int BM, int BN, int EPI, int OCC>
__global__ __launch_bounds__(256, OCC)
void gemm_bf16(const ushort_t* __restrict__ A, const ushort_t* __restrict__ Wt,
               const float* __restrict__ bias, void* __restrict__ outv,
               const float* __restrict__ emb_h, const float* __restrict__ emb_w,
               const int* __restrict__ tok,
               int M, int N, int K) {
    constexpr int WM = BM / 2, WN = BN / 2;
    constexpr int FM = WM / 16, FN = WN / 16;
    constexpr int BUF = (BM + BN) * 64;
    constexpr int LPT = (BM + BN) / 32;
    using f32x4  = __attribute__((ext_vector_type(4))) float;
    using bf16x8 = __attribute__((ext_vector_type(8))) short;

    __shared__ __align__(16) ushort_t lds[3 * BUF];

    int tid = threadIdx.x;
    int lane = tid & 63, wid = tid >> 6;
    int wr = wid >> 1, wc = wid & 1;
    int l16 = lane & 15, lg = lane >> 4;
    int sw = l16 & 7;

    int nx = N / BN;
    int cpx = gridDim.x >> 3;
    int wg = blockIdx.x;
    int wgid = (wg & 7) * cpx + (wg >> 3);
    int bx = wgid % nx, by = wgid / nx;
    int bm0 = by * BM, bn0 = bx * BN;

    f32x4 acc[FM][FN];
    #pragma unroll
    for (int m = 0; m < FM; ++m)
        #pragma unroll
        for (int n = 0; n < FN; ++n)
            #pragma unroll
            for (int r = 0; r < 4; ++r) acc[m][n][r] = 0.f;

    const ushort_t* Abase = A + (size_t)bm0 * K;
    int KB = K >> 6;
    const ushort_t* Bt0 = Wt + (((size_t)(bn0 >> 6) * KB) << 12);

    #define STAGE(bufi, kt)                                                             \
        do {                                                                            \
            _Pragma("unroll")                                                           \
            for (int s2 = 0; s2 < BM / 32; ++s2) {                                      \
                int ca = s2 * 256 + tid;                                                \
                int rw = ca >> 3, kcs = (ca & 7) ^ (rw & 7);                            \
                async_ld16(&lds[(bufi) * BUF + ca * 8],                                 \
                           Abase + (size_t)rw * K + (kt) * 64 + kcs * 8);               \
            }                                                                           \
            _Pragma("unroll")                                                           \
            for (int s2 = 0; s2 < BN / 32; ++s2) {                                      \
                int ca = s2 * 256 + tid;                                                \
                int rw = ca >> 3, kcs = (ca & 7) ^ (rw & 7);                            \
                async_ld16(&lds[(bufi) * BUF + BM * 64 + ca * 8],                       \
                           Bt0 + ((((size_t)(rw >> 6) * KB + (kt)) << 12))              \
                               + (rw & 63) * 64 + kcs * 8);                             \
            }                                                                           \
        } while (0)

    int nk = K >> 6;
    STAGE(0, 0);
    STAGE(1, 1);
    int bufi = 0;
    for (int kt = 0; kt < nk; ++kt) {
        int nxt = bufi + 2; if (nxt >= 3) nxt -= 3;
        if (kt + 2 < nk) {
            STAGE(nxt, kt + 2);
            if constexpr (LPT == 4) WAITVM(8); else WAITVM(12);
        } else if (kt + 1 < nk) {
            if constexpr (LPT == 4) WAITVM(4); else WAITVM(6);
        } else {
            WAITVM(0);
        }
        __builtin_amdgcn_s_barrier();
        __builtin_amdgcn_s_setprio(1);
        #pragma unroll
        for (int kk = 0; kk < 2; ++kk) {
            bf16x8 af[FM], bfr[FN];
            #pragma unroll
            for (int m = 0; m < FM; ++m) {
                int row = wr * WM + m * 16 + l16;
                int csw = (kk * 4 + lg) ^ sw;
                af[m] = *(const bf16x8*)&lds[bufi * BUF + row * 64 + csw * 8];
            }
            #pragma unroll
            for (int n = 0; n < FN; ++n) {
                int row = wc * WN + n * 16 + l16;
                int csw = (kk * 4 + lg) ^ sw;
                bfr[n] = *(const bf16x8*)&lds[bufi * BUF + BM * 64 + row * 64 + csw * 8];
            }
            #pragma unroll
            for (int m = 0; m < FM; ++m)
                #pragma unroll
                for (int n = 0; n < FN; ++n)
                    acc[m][n] = __builtin_amdgcn_mfma_f32_16x16x32_bf16(af[m], bfr[n], acc[m][n], 0, 0, 0);
        }
        __builtin_amdgcn_s_setprio(0);
        __builtin_amdgcn_s_barrier();
        ++bufi; if (bufi >= 3) bufi = 0;
    }
    #undef STAGE

    int r0 = bm0 + wr * WM, c0 = bn0 + wc * WN;
    #pragma unroll
    for (int m = 0; m < FM; ++m) {
        #pragma unroll
        for (int n = 0; n < FN; ++n) {
            int cc = c0 + n * 16 + l16;
            float bcol = bias[cc];
            #pragma unroll
            for (int r = 0; r < 4; ++r) {
                int row = r0 + m * 16 + lg * 4 + r;
                float v = acc[m][n][r] + bcol;
                if (EPI == 0) {
                    ((ushort_t*)outv)[(size_t)row * N + cc] = f2bf(v);
                } else if (EPI == 1) {
                    int p0 = tok[row * 3 + 1], p1 = tok[row * 3 + 2];
                    v += emb_h[p0 * DMODEL + cc] + emb_w[p1 * DMODEL + cc];
                    ((float*)outv)[(size_t)row * N + cc] = v;
                } else if (EPI == 2) {
                    float* op = (float*)outv + (size_t)row * N + cc;
                    *op = *op + v;
                } else {
                    ((ushort_t*)outv)[(size_t)row * N + cc] = f2bf(gelu_exact(v));
                }
            }
        }
    }
}

// ---------------------------------------------------------------- sparse local attention (list-driven)
__global__ __launch_bounds__(256)
void attn_kernel(const ushort_t* __restrict__ qkv, const short* __restrict__ nbr,
                 const int* __restrict__ nbr_cnt, ushort_t* __restrict__ o_out) {
    int tid = threadIdx.x;
    int u = tid >> 2, part = tid & 3;
    int q = blockIdx.x * 16 + (u & 15);
    int h = blockIdx.y * 4 + (u >> 4);
    int b = blockIdx.z;
    int m = b * SEQ + q;
    ushort_t* op = o_out + (size_t)m * DMODEL + h * DHEAD + part * 16;
    int cnt = nbr_cnt[m];
    if (cnt == 0) {
        uint4 z = {0u, 0u, 0u, 0u};
        ((uint4*)op)[0] = z;
        ((uint4*)op)[1] = z;
        return;
    }
    const short* lst = nbr + (size_t)m * 28;
    const ushort_t* qp = qkv + (size_t)m * (3 * DMODEL) + h * DHEAD + part * 16;
    float qv[16], ov[16];
    {
        uint4 u0 = ((const uint4*)qp)[0];
        uint4 u1 = ((const uint4*)qp)[1];
        qv[0] = bf2f(u0.x & 0xffff) * 0.125f; qv[1] = bf2f(u0.x >> 16) * 0.125f;
        qv[2] = bf2f(u0.y & 0xffff) * 0.125f; qv[3] = bf2f(u0.y >> 16) * 0.125f;
        qv[4] = bf2f(u0.z & 0xffff) * 0.125f; qv[5] = bf2f(u0.z >> 16) * 0.125f;
        qv[6] = bf2f(u0.w & 0xffff) * 0.125f; qv[7] = bf2f(u0.w >> 16) * 0.125f;
        qv[8]  = bf2f(u1.x & 0xffff) * 0.125f; qv[9]  = bf2f(u1.x >> 16) * 0.125f;
        qv[10] = bf2f(u1.y & 0xffff) * 0.125f; qv[11] = bf2f(u1.y >> 16) * 0.125f;
        qv[12] = bf2f(u1.z & 0xffff) * 0.125f; qv[13] = bf2f(u1.z >> 16) * 0.125f;
        qv[14] = bf2f(u1.w & 0xffff) * 0.125f; qv[15] = bf2f(u1.w >> 16) * 0.125f;
    }
    #pragma unroll
    for (int i = 0; i < 16; ++i) ov[i] = 0.f;
    float mx = -1e30f, den = 0.f;
    for (int it = 0; it < cnt; ++it) {
        int km = b * SEQ + (int)lst[it];
        const ushort_t* kp = qkv + (size_t)km * (3 * DMODEL) + DMODEL + h * DHEAD + part * 16;
        float dot;
        {
            uint4 u0 = ((const uint4*)kp)[0];
            uint4 u1 = ((const uint4*)kp)[1];
            dot = qv[0] * bf2f(u0.x & 0xffff);
            dot = fmaf(qv[1], bf2f(u0.x >> 16), dot);
            dot = fmaf(qv[2], bf2f(u0.y & 0xffff), dot);
            dot = fmaf(qv[3], bf2f(u0.y >> 16), dot);
            dot = fmaf(qv[4], bf2f(u0.z & 0xffff), dot);
            dot = fmaf(qv[5], bf2f(u0.z >> 16), dot);
            dot = fmaf(qv[6], bf2f(u0.w & 0xffff), dot);
            dot = fmaf(qv[7], bf2f(u0.w >> 16), dot);
            dot = fmaf(qv[8],  bf2f(u1.x & 0xffff), dot);
            dot = fmaf(qv[9],  bf2f(u1.x >> 16), dot);
            dot = fmaf(qv[10], bf2f(u1.y & 0xffff), dot);
            dot = fmaf(qv[11], bf2f(u1.y >> 16), dot);
            dot = fmaf(qv[12], bf2f(u1.z & 0xffff), dot);
            dot = fmaf(qv[13], bf2f(u1.z >> 16), dot);
            dot = fmaf(qv[14], bf2f(u1.w & 0xffff), dot);
            dot = fmaf(qv[15], bf2f(u1.w >> 16), dot);
        }
        dot += __shfl_xor(dot, 1);
        dot += __shfl_xor(dot, 2);
        float sc = dot;
        float nm = fmaxf(mx, sc);
        float c1 = expf(mx - nm);
        float c2 = expf(sc - nm);
        den = den * c1 + c2;
        const ushort_t* vp = qkv + (size_t)km * (3 * DMODEL) + 2 * DMODEL + h * DHEAD + part * 16;
        {
            uint4 u0 = ((const uint4*)vp)[0];
            uint4 u1 = ((const uint4*)vp)[1];
            ov[0] = ov[0] * c1 + c2 * bf2f(u0.x & 0xffff);
            ov[1] = ov[1] * c1 + c2 * bf2f(u0.x >> 16);
            ov[2] = ov[2] * c1 + c2 * bf2f(u0.y & 0xffff);
            ov[3] = ov[3] * c1 + c2 * bf2f(u0.y >> 16);
            ov[4] = ov[4] * c1 + c2 * bf2f(u0.z & 0xffff);
            ov[5] = ov[5] * c1 + c2 * bf2f(u0.z >> 16);
            ov[6] = ov[6] * c1 + c2 * bf2f(u0.w & 0xffff);
            ov[7] = ov[7] * c1 + c2 * bf2f(u0.w >> 16);
            ov[8]  = ov[8]  * c1 + c2 * bf2f(u1.x & 0xffff);
            ov[9]  = ov[9]  * c1 + c2 * bf2f(u1.x >> 16);
            ov[10] = ov[10] * c1 + c2 * bf2f(u1.y & 0xffff);
            ov[11] = ov[11] * c1 + c2 * bf2f(u1.y >> 16);
            ov[12] = ov[12] * c1 + c2 * bf2f(u1.z & 0xffff);
            ov[13] = ov[13] * c1 + c2 * bf2f(u1.z >> 16);
            ov[14] = ov[14] * c1 + c2 * bf2f(u1.w & 0xffff);
            ov[15] = ov[15] * c1 + c2 * bf2f(u1.w >> 16);
        }
        mx = nm;
    }
    float inv = 1.f / den;
    uint4 o0, o1;
    o0.x = (uint_t)f2bf(ov[0] * inv) | ((uint_t)f2bf(ov[1] * inv) << 16);
    o0.y = (uint_t)f2bf(ov[2] * inv) | ((uint_t)f2bf(ov[3] * inv) << 16);
    o0.z = (uint_t)f2bf(ov[4] * inv) | ((uint_t)f2bf(ov[5] * inv) << 16);
    o0.w = (uint_t)f2bf(ov[6] * inv) | ((uint_t)f2bf(ov[7] * inv) << 16);
    o1.x = (uint_t)f2bf(ov[8]  * inv) | ((uint_t)f2bf(ov[9]  * inv) << 16);
    o1.y = (uint_t)f2bf(ov[10] * inv) | ((uint_t)f2bf(ov[11] * inv) << 16);
    o1.z = (uint_t)f2bf(ov[12] * inv) | ((uint_t)f2bf(ov[13] * inv) << 16);
    o1.w = (uint_t)f2bf(ov[14] * inv) | ((uint_t)f2bf(ov[15] * inv) << 16);
    ((uint4*)op)[0] = o0;
    ((uint4*)op)[1] = o1;
}

// ---------------------------------------------------------------- launch
extern "C" void kernel_launch(void* const* d_in, const int* in_sizes, int n_in,
                              void* d_out, int out_size, void* d_ws, size_t ws_size,
                              hipStream_t stream) {
    const float* x_in      = (const float*)d_in[0];
    const int*   t         = (const int*)d_in[1];
    const int*   tok       = (const int*)d_in[2];
    const float* proj_in_w = (const float*)d_in[3];
    const float* proj_in_b = (const float*)d_in[4];
    const float* h_emb     = (const float*)d_in[5];
    const float* w_emb     = (const float*)d_in[6];
    const float* adaln1_w  = (const float*)d_in[7];
    const float* adaln1_b  = (const float*)d_in[8];
    const float* ln1_g     = (const float*)d_in[9];
    const float* ln1_b     = (const float*)d_in[10];
    const float* qkv_w     = (const float*)d_in[11];
    const float* qkv_b     = (const float*)d_in[12];
    const float* o_w       = (const float*)d_in[13];
    const float* o_b       = (const float*)d_in[14];
    const float* adaln2_w  = (const float*)d_in[15];
    const float* adaln2_b  = (const float*)d_in[16];
    const float* ln2_g     = (const float*)d_in[17];
    const float* ln2_b     = (const float*)d_in[18];
    const float* fc1_w     = (const float*)d_in[19];
    const float* fc1_b     = (const float*)d_in[20];
    const float* fc2_w     = (const float*)d_in[21];
    const float* fc2_b     = (const float*)d_in[22];
    const float* nout_w    = (const float*)d_in[23];
    const float* nout_b    = (const float*)d_in[24];
    const float* nout_g    = (const float*)d_in[25];
    const float* nout_beta = (const float*)d_in[26];

    const int M = BATCH * SEQ;   // 4096

    float* stemb   = (float*)d_ws;
    float* e_all   = stemb + BATCH * DMODEL;
    float* partial = e_all + 21 * BATCH * 2 * DMODEL;
    int*   nbr_cnt = (int*)(partial + 21 * 8 * 4 * 2 * DMODEL);
    short* nbr     = (short*)(nbr_cnt + M);
    ushort_t* h_bf   = (ushort_t*)(nbr + (size_t)M * 28);
    ushort_t* qkv_bf = h_bf + (size_t)M * DMODEL;
    ushort_t* hid_bf = qkv_bf + (size_t)M * 3 * DMODEL;
    ushort_t* projT  = hid_bf + (size_t)M * HIDDEN;
    ushort_t* qkvT_a = projT + (size_t)DMODEL * DMODEL;                 // 10 layers
    ushort_t* oT_a   = qkvT_a + (size_t)NLAYER * 3 * DMODEL * DMODEL;
    ushort_t* fc1T_a = oT_a + (size_t)NLAYER * DMODEL * DMODEL;
    ushort_t* fc2T_a = fc1T_a + (size_t)NLAYER * DMODEL * HIDDEN;
    float* x = (float*)d_out;

    temb_silu_kernel<<<BATCH, 384, 0, stream>>>(t, stemb);
    prep_all_kernel<<<PREP_GRID, 256, 0, stream>>>(
        qkv_w, o_w, fc1_w, fc2_w, qkvT_a, oT_a, fc1T_a, fc2T_a,
        proj_in_w, projT, x_in, h_bf, stemb, adaln1_w, adaln2_w, nout_w, partial,
        tok, nbr, nbr_cnt);
    adaln_reduce_kernel<<<dim3(6, 2 * NLAYER + 1), 256, 0, stream>>>(
        partial, adaln1_b, adaln2_b, nout_b, e_all);

    // proj_in: v3 64x64, 768 blocks
    gemm_bf16<64, 64, 1, 3><<<(DMODEL / 64) * (M / 64), 256, 0, stream>>>(
        h_bf, projT, proj_in_b, x, h_emb, w_emb, tok, M, DMODEL, DMODEL);

    for (int i = 0; i < NLAYER; ++i) {
        ln_adaln_kernel<1><<<M / 4, 256, 0, stream>>>(
            x, h_bf, ln1_g + i * DMODEL, ln1_b + i * DMODEL,
            e_all + (size_t)(2 * i) * BATCH * 2 * DMODEL);
        // qkv: 128x128 replica, 576 blocks
        gemm_bf16_big<0><<<(3 * DMODEL / 128) * (M / 128), 256, 0, stream>>>(
            h_bf, qkvT_a + (size_t)i * 3 * DMODEL * DMODEL, qkv_b + i * 3 * DMODEL,
            qkv_bf, M, 3 * DMODEL, DMODEL);
        attn_kernel<<<dim3(SEQ / 16, NHEAD / 4, BATCH), 256, 0, stream>>>(qkv_bf, nbr, nbr_cnt, h_bf);
        // o-proj: v3 64x64, 768 blocks (residual)
        gemm_bf16<64, 64, 2, 3><<<(DMODEL / 64) * (M / 64), 256, 0, stream>>>(
            h_bf, oT_a + (size_t)i * DMODEL * DMODEL, o_b + i * DMODEL,
            x, nullptr, nullptr, nullptr, M, DMODEL, DMODEL);
        ln_adaln_kernel<1><<<M / 4, 256, 0, stream>>>(
            x, h_bf, ln2_g + i * DMODEL, ln2_b + i * DMODEL,
            e_all + (size_t)(2 * i + 1) * BATCH * 2 * DMODEL);
        // fc1: 128x128 replica + gelu, 768 blocks
        gemm_bf16_big<3><<<(HIDDEN / 128) * (M / 128), 256, 0, stream>>>(
            h_bf, fc1T_a + (size_t)i * DMODEL * HIDDEN, fc1_b + i * HIDDEN,
            hid_bf, M, HIDDEN, DMODEL);
        // fc2: v3 pipelined 128x64, 384 blocks (K=3072: 48-step pipeline)
        gemm_bf16<128, 64, 2, 2><<<(DMODEL / 64) * (M / 128), 256, 0, stream>>>(
            hid_bf, fc2T_a + (size_t)i * DMODEL * HIDDEN, fc2_b + i * DMODEL,
            x, nullptr, nullptr, nullptr, M, DMODEL, HIDDEN);
    }

    ln_adaln_kernel<0><<<M / 4, 256, 0, stream>>>(
        x, x, nout_g, nout_beta, e_all + (size_t)(2 * NLAYER) * BATCH * 2 * DMODEL);
}

// Round 18
// 1615.595 us; speedup vs baseline: 1.0533x; 1.0024x over previous
//
#include <hip/hip_runtime.h>
#include <hip/hip_bf16.h>
#include <math.h>

#define MASK_ID (-100)
#define SEQ 1024
#define BATCH 4
#define DMODEL 768
#define NHEAD 12
#define DHEAD 64
#define NLAYER 10
#define HIDDEN 3072

typedef unsigned short ushort_t;
typedef unsigned int uint_t;

// ---------------------------------------------------------------- bf16 helpers
__device__ __forceinline__ ushort_t f2bf(float f) {
    uint_t u = __float_as_uint(f);
    u = u + 0x7fffu + ((u >> 16) & 1u);   // round-to-nearest-even
    return (ushort_t)(u >> 16);
}
__device__ __forceinline__ float bf2f(ushort_t u) {
    return __uint_as_float(((uint_t)u) << 16);
}

// async global->LDS, 16 bytes per lane
__device__ __forceinline__ void async_ld16(ushort_t* lds, const ushort_t* g) {
    __builtin_amdgcn_global_load_lds((__attribute__((address_space(1))) const void*)g,
                                     (__attribute__((address_space(3))) void*)lds, 16, 0, 0);
}

#define WAITVM(n) asm volatile("s_waitcnt vmcnt(" #n ")" ::: "memory")

// Wt tiled layout: [nb][kb][ni(64)][ki(64)], 4096 bf16 (8 KB) per tile, fully
// contiguous. offset(n,k) = ((nb*KB + kb)<<12) + ni*64 + ki,  KB = K/64.

// ---------------------------------------------------------------- temb+silu
__global__ void temb_silu_kernel(const int* __restrict__ t, float* __restrict__ stemb) {
    int b = blockIdx.x;
    int j = threadIdx.x;           // 0..383
    float tv = (float)t[b * SEQ];
    float freq = expf(-logf(10000.f) * (float)j / 383.f);
    float arg = tv * freq;
    float s = sinf(arg), c = cosf(arg);
    stemb[b * DMODEL + j]       = s / (1.f + expf(-s));
    stemb[b * DMODEL + 384 + j] = c / (1.f + expf(-c));
}

// ---------------------------------------------------------------- prologue mega-kernel
//   [0, 17280)       : weight transposes -> tiled Wt (10 layers x 1728 tiles)
//   [17280, 17424)   : proj_in_w -> tiled (144 tiles)
//   [17424, 18960)   : x fp32 -> bf16 (1536 blocks)
//   [18960, 19968)   : adaln stage-1 partials (1008)
//   [19968, 19984)   : attention neighbor lists (16 blocks)
#define PREP_GRID 19984
__global__ __launch_bounds__(256)
void prep_all_kernel(const float* __restrict__ w0, const float* __restrict__ w1,
                     const float* __restrict__ w2, const float* __restrict__ w3,
                     ushort_t* __restrict__ o0, ushort_t* __restrict__ o1,
                     ushort_t* __restrict__ o2, ushort_t* __restrict__ o3,
                     const float* __restrict__ proj_in_w, ushort_t* __restrict__ projT,
                     const float* __restrict__ x_in, ushort_t* __restrict__ h_bf,
                     const float* __restrict__ stemb,
                     const float* __restrict__ a1w, const float* __restrict__ a2w,
                     const float* __restrict__ nw, float* __restrict__ partial,
                     const int* __restrict__ tok, short* __restrict__ nbr,
                     int* __restrict__ nbr_cnt) {
    __shared__ __align__(16) char smem[64 * 65 * 2];
    int gid = blockIdx.x;
    int tid = threadIdx.x;

    if (gid < 17424) {
        // ---- transpose to TILED Wt. W HBM layout: [R=K][C=N] fp32.
        const float* in; ushort_t* out; int R, C, tile_id, TX;
        if (gid < 17280) {
            int layer = gid / 1728;
            int id = gid % 1728;
            if (id < 432) {
                in = w0 + (size_t)layer * DMODEL * 3 * DMODEL; out = o0 + (size_t)layer * 3 * DMODEL * DMODEL;
                R = DMODEL; C = 3 * DMODEL; tile_id = id; TX = 36;
            } else if (id < 576) {
                in = w1 + (size_t)layer * DMODEL * DMODEL; out = o1 + (size_t)layer * DMODEL * DMODEL;
                R = DMODEL; C = DMODEL; tile_id = id - 432; TX = 12;
            } else if (id < 1152) {
                in = w2 + (size_t)layer * DMODEL * HIDDEN; out = o2 + (size_t)layer * HIDDEN * DMODEL;
                R = DMODEL; C = HIDDEN; tile_id = id - 576; TX = 48;
            } else {
                in = w3 + (size_t)layer * HIDDEN * DMODEL; out = o3 + (size_t)layer * DMODEL * HIDDEN;
                R = HIDDEN; C = DMODEL; tile_id = id - 1152; TX = 12;
            }
        } else {
            in = proj_in_w; out = projT; R = DMODEL; C = DMODEL; tile_id = gid - 17280; TX = 12;
        }
        int c0 = (tile_id % TX) * 64, r0 = (tile_id / TX) * 64;   // c = n, r = k
        int KB = R >> 6;
        int nb = c0 >> 6, kb = r0 >> 6;
        ushort_t* tlb = (ushort_t*)smem;   // [r(k)][65]
        #pragma unroll
        for (int i = 0; i < 4; ++i) {
            int idx = i * 256 + tid;
            int r = idx >> 4, c4 = (idx & 15) * 4;
            float4 v = *(const float4*)&in[(size_t)(r0 + r) * C + c0 + c4];
            tlb[r * 65 + c4 + 0] = f2bf(v.x);
            tlb[r * 65 + c4 + 1] = f2bf(v.y);
            tlb[r * 65 + c4 + 2] = f2bf(v.z);
            tlb[r * 65 + c4 + 3] = f2bf(v.w);
        }
        __syncthreads();
        ushort_t* ob = out + (((size_t)(nb * KB + kb)) << 12);
        #pragma unroll
        for (int j = 0; j < 8; ++j) {
            int idx = j * 256 + tid;
            int ni = idx >> 5, kp = idx & 31;
            uint_t pk = (uint_t)tlb[(kp * 2) * 65 + ni] | ((uint_t)tlb[(kp * 2 + 1) * 65 + ni] << 16);
            *(uint_t*)&ob[ni * 64 + kp * 2] = pk;
        }
    } else if (gid < 18960) {
        int i = (gid - 17424) * 256 + tid;
        float4 a = ((const float4*)x_in)[2 * i];
        float4 b = ((const float4*)x_in)[2 * i + 1];
        uint4 o;
        o.x = (uint_t)f2bf(a.x) | ((uint_t)f2bf(a.y) << 16);
        o.y = (uint_t)f2bf(a.z) | ((uint_t)f2bf(a.w) << 16);
        o.z = (uint_t)f2bf(b.x) | ((uint_t)f2bf(b.y) << 16);
        o.w = (uint_t)f2bf(b.z) | ((uint_t)f2bf(b.w) << 16);
        ((uint4*)h_bf)[i] = o;
    } else if (gid < 19968) {
        int s3 = gid - 18960;
        int chunk = s3 % 6;
        int kc = (s3 / 6) % 8;
        int slot = s3 / 48;
        int col = chunk * 256 + tid;
        const float* W;
        if (slot == 20) W = nw;
        else {
            int i = slot >> 1;
            W = ((slot & 1) ? a2w : a1w) + (size_t)i * DMODEL * 2 * DMODEL;
        }
        float* sb = (float*)smem;
        for (int idx = tid; idx < 4 * 96; idx += 256) {
            int bb = idx / 96, kk = idx % 96;
            sb[idx] = stemb[bb * DMODEL + kc * 96 + kk];
        }
        __syncthreads();
        const float* Wp = W + (size_t)(kc * 96) * (2 * DMODEL) + col;
        float a0 = 0.f, a1 = 0.f, a2 = 0.f, a3 = 0.f;
        #pragma unroll 4
        for (int kk = 0; kk < 96; ++kk) {
            float w = Wp[(size_t)kk * (2 * DMODEL)];
            a0 = fmaf(sb[kk], w, a0);
            a1 = fmaf(sb[96 + kk], w, a1);
            a2 = fmaf(sb[192 + kk], w, a2);
            a3 = fmaf(sb[288 + kk], w, a3);
        }
        size_t base = ((size_t)(slot * 8 + kc) * 4) * (2 * DMODEL) + col;
        partial[base + 0 * 2 * DMODEL] = a0;
        partial[base + 1 * 2 * DMODEL] = a1;
        partial[base + 2 * 2 * DMODEL] = a2;
        partial[base + 3 * 2 * DMODEL] = a3;
    } else {
        // ---- neighbor lists (order matches original (dh,dw) loop)
        int m = (gid - 19968) * 256 + tid;        // 0..4095
        int b = m >> 10, q = m & 1023;
        int sid = tok[m * 3];
        int cnt = 0;
        short* lst = nbr + (size_t)m * 28;
        if (sid != MASK_ID) {
            int qh = tok[m * 3 + 1], qw = tok[m * 3 + 2];
            for (int dh = -2; dh <= 2; ++dh) {
                for (int dw = -2; dw <= 2; ++dw) {
                    int kq = q + dh * 16 + dw;
                    if (kq < 0 || kq >= SEQ) continue;
                    int km = b * SEQ + kq;
                    if (tok[km * 3] != sid) continue;
                    int kh2 = tok[km * 3 + 1], kw2 = tok[km * 3 + 2];
                    int adh = kh2 - qh; if (adh < 0) adh = -adh;
                    int adw = kw2 - qw; if (adw < 0) adw = -adw;
                    if (adh > 2 || adw > 2) continue;
                    lst[cnt++] = (short)kq;
                }
            }
        }
        nbr_cnt[m] = cnt;
    }
}

__global__ __launch_bounds__(256)
void adaln_reduce_kernel(const float* __restrict__ partial,
                         const float* __restrict__ a1b, const float* __restrict__ a2b,
                         const float* __restrict__ nb,
                         float* __restrict__ e_all) {
    int chunk = blockIdx.x;   // 0..5
    int slot  = blockIdx.y;   // 0..20
    int col = chunk * 256 + threadIdx.x;
    const float* bb;
    if (slot == 20) bb = nb;
    else {
        int i = slot >> 1;
        bb = ((slot & 1) ? a2b : a1b) + i * 2 * DMODEL;
    }
    float bias = bb[col];
    float s0 = bias, s1 = bias, s2 = bias, s3 = bias;
    #pragma unroll
    for (int kc = 0; kc < 8; ++kc) {
        size_t base = ((size_t)(slot * 8 + kc) * 4) * (2 * DMODEL) + col;
        s0 += partial[base + 0 * 2 * DMODEL];
        s1 += partial[base + 1 * 2 * DMODEL];
        s2 += partial[base + 2 * 2 * DMODEL];
        s3 += partial[base + 3 * 2 * DMODEL];
    }
    size_t o = (size_t)slot * 4 * (2 * DMODEL) + col;
    e_all[o + 0 * 2 * DMODEL] = s0;
    e_all[o + 1 * 2 * DMODEL] = s1;
    e_all[o + 2 * 2 * DMODEL] = s2;
    e_all[o + 3 * 2 * DMODEL] = s3;
}

// ---------------------------------------------------------------- fused LN + adaLN, wave-per-row
// Vectorized (G13): lane owns 4 consecutive elems; float4 x/g/be/esc loads,
// uint2-packed bf16 (or float4 fp32) stores.
template<int OUT_BF>
__global__ __launch_bounds__(256)
void ln_adaln_kernel(const float* __restrict__ in, void* __restrict__ outv,
                     const float* __restrict__ g, const float* __restrict__ be,
                     const float* __restrict__ e) {
    int wid = threadIdx.x >> 6, lane = threadIdx.x & 63;
    int row = blockIdx.x * 4 + wid;
    int b = row >> 10;
    const float* xr = in + (size_t)row * DMODEL;
    float4 v[3];
    float s = 0.f, ss = 0.f;
    #pragma unroll
    for (int j = 0; j < 3; ++j) {
        v[j] = *(const float4*)&xr[lane * 4 + j * 256];
        s += (v[j].x + v[j].y) + (v[j].z + v[j].w);
        ss += (v[j].x * v[j].x + v[j].y * v[j].y) + (v[j].z * v[j].z + v[j].w * v[j].w);
    }
    #pragma unroll
    for (int o = 1; o < 64; o <<= 1) { s += __shfl_xor(s, o); ss += __shfl_xor(ss, o); }
    float mu = s * (1.f / DMODEL);
    float var = ss * (1.f / DMODEL) - mu * mu;
    float rs = rsqrtf(var + 1e-5f);
    const float* esc = e + (size_t)b * (2 * DMODEL);
    #pragma unroll
    for (int j = 0; j < 3; ++j) {
        int c0 = lane * 4 + j * 256;
        float4 gv = *(const float4*)&g[c0];
        float4 bv = *(const float4*)&be[c0];
        float4 sv = *(const float4*)&esc[c0];
        float4 hv = *(const float4*)&esc[DMODEL + c0];
        float y0 = ((v[j].x - mu) * rs * gv.x + bv.x) * (1.f + sv.x) + hv.x;
        float y1 = ((v[j].y - mu) * rs * gv.y + bv.y) * (1.f + sv.y) + hv.y;
        float y2 = ((v[j].z - mu) * rs * gv.z + bv.z) * (1.f + sv.z) + hv.z;
        float y3 = ((v[j].w - mu) * rs * gv.w + bv.w) * (1.f + sv.w) + hv.w;
        if (OUT_BF) {
            uint2 pk;
            pk.x = (uint_t)f2bf(y0) | ((uint_t)f2bf(y1) << 16);
            pk.y = (uint_t)f2bf(y2) | ((uint_t)f2bf(y3) << 16);
            *(uint2*)&((ushort_t*)outv)[(size_t)row * DMODEL + c0] = pk;
        } else {
            float4 o4 = {y0, y1, y2, y3};
            *(float4*)&((float*)outv)[(size_t)row * DMODEL + c0] = o4;
        }
    }
}

__device__ __forceinline__ float gelu_exact(float x) {
    return 0.5f * x * (1.f + erff(x * 0.70710678118654752f));
}

// ---------------------------------------------------------------- GEMM A: m97-replica, 128x128 tile
// Wt in tiled layout.
template<int EPI>
__global__ __launch_bounds__(256, 3)
void gemm_bf16_big(const ushort_t* __restrict__ A, const ushort_t* __restrict__ Wt,
                   const float* __restrict__ bias, void* __restrict__ outv,
                   int M, int N, int K) {
    constexpr int BM = 128, BN = 128;
    using f32x4  = __attribute__((ext_vector_type(4))) float;
    using bf16x8 = __attribute__((ext_vector_type(8))) short;

    __shared__ __align__(16) ushort_t lds[(BM + BN) * 64];

    int tid = threadIdx.x;
    int lane = tid & 63, wid = tid >> 6;
    int wr = wid >> 1, wc = wid & 1;
    int l16 = lane & 15, lg = lane >> 4;
    int sw = l16 & 7;

    int nx = N / BN;
    int cpx = gridDim.x >> 3;
    int wg = blockIdx.x;
    int wgid = (wg & 7) * cpx + (wg >> 3);
    int bx = wgid % nx, by = wgid / nx;
    int bm0 = by * BM, bn0 = bx * BN;

    f32x4 acc[4][4];
    #pragma unroll
    for (int m = 0; m < 4; ++m)
        #pragma unroll
        for (int n = 0; n < 4; ++n)
            #pragma unroll
            for (int r = 0; r < 4; ++r) acc[m][n][r] = 0.f;

    const ushort_t* Abase = A + (size_t)bm0 * K;
    int KB = K >> 6;
    const ushort_t* Bt0 = Wt + (((size_t)(bn0 >> 6) * KB) << 12);

    int nk = K >> 6;
    for (int kt = 0; kt < nk; ++kt) {
        #pragma unroll
        for (int s2 = 0; s2 < 4; ++s2) {
            int ca = s2 * 256 + tid;
            int rw = ca >> 3, kcs = (ca & 7) ^ (rw & 7);
            async_ld16(&lds[ca * 8], Abase + (size_t)rw * K + kt * 64 + kcs * 8);
        }
        #pragma unroll
        for (int s2 = 0; s2 < 4; ++s2) {
            int ca = s2 * 256 + tid;
            int rw = ca >> 3, kcs = (ca & 7) ^ (rw & 7);
            async_ld16(&lds[BM * 64 + ca * 8],
                       Bt0 + ((((size_t)(rw >> 6) * KB + kt) << 12)) + (rw & 63) * 64 + kcs * 8);
        }
        WAITVM(0);
        __syncthreads();
        #pragma unroll
        for (int kk = 0; kk < 2; ++kk) {
            int csw = (kk * 4 + lg) ^ sw;
            bf16x8 af[4], bfr[4];
            #pragma unroll
            for (int m = 0; m < 4; ++m)
                af[m] = *(const bf16x8*)&lds[(wr * 64 + m * 16 + l16) * 64 + csw * 8];
            #pragma unroll
            for (int n = 0; n < 4; ++n)
                bfr[n] = *(const bf16x8*)&lds[BM * 64 + (wc * 64 + n * 16 + l16) * 64 + csw * 8];
            #pragma unroll
            for (int m = 0; m < 4; ++m)
                #pragma unroll
                for (int n = 0; n < 4; ++n)
                    acc[m][n] = __builtin_amdgcn_mfma_f32_16x16x32_bf16(af[m], bfr[n], acc[m][n], 0, 0, 0);
        }
        __syncthreads();
    }

    int r0 = bm0 + wr * 64, c0 = bn0 + wc * 64;
    #pragma unroll
    for (int m = 0; m < 4; ++m) {
        #pragma unroll
        for (int n = 0; n < 4; ++n) {
            int cc = c0 + n * 16 + l16;
            float bcol = bias[cc];
            #pragma unroll
            for (int r = 0; r < 4; ++r) {
                int row = r0 + m * 16 + lg * 4 + r;
                float v = acc[m][n][r] + bcol;
                if (EPI == 0) ((ushort_t*)outv)[(size_t)row * N + cc] = f2bf(v);
                else          ((ushort_t*)outv)[(size_t)row * N + cc] = f2bf(gelu_exact(v));
            }
        }
    }
}

// ---------------------------------------------------------------- GEMM B: v3 3-buffer counted-vmcnt
// Wt in tiled layout.
template<int BM, int BN, int EPI, int OCC>
__global__ __launch_bounds__(256, OCC)
void gemm_bf16(const ushort_t* __restrict__ A, const ushort_t* __restrict__ Wt,
               const float* __restrict__ bias, void* __restrict__ outv,
               const float* __restrict__ emb_h, const float* __restrict__ emb_w,
               const int* __restrict__ tok,
               int M, int N, int K) {
    constexpr int WM = BM / 2, WN = BN / 2;
    constexpr int FM = WM / 16, FN = WN / 16;
    constexpr int BUF = (BM + BN) * 64;
    constexpr int LPT = (BM + BN) / 32;
    using f32x4  = __attribute__((ext_vector_type(4))) float;
    using bf16x8 = __attribute__((ext_vector_type(8))) short;

    __shared__ __align__(16) ushort_t lds[3 * BUF];

    int tid = threadIdx.x;
    int lane = tid & 63, wid = tid >> 6;
    int wr = wid >> 1, wc = wid & 1;
    int l16 = lane & 15, lg = lane >> 4;
    int sw = l16 & 7;

    int nx = N / BN;
    int cpx = gridDim.x >> 3;
    int wg = blockIdx.x;
    int wgid = (wg & 7) * cpx + (wg >> 3);
    int bx = wgid % nx, by = wgid / nx;
    int bm0 = by * BM, bn0 = bx * BN;

    f32x4 acc[FM][FN];
    #pragma unroll
    for (int m = 0; m < FM; ++m)
        #pragma unroll
        for (int n = 0; n < FN; ++n)
            #pragma unroll
            for (int r = 0; r < 4; ++r) acc[m][n][r] = 0.f;

    const ushort_t* Abase = A + (size_t)bm0 * K;
    int KB = K >> 6;
    const ushort_t* Bt0 = Wt + (((size_t)(bn0 >> 6) * KB) << 12);

    #define STAGE(bufi, kt)                                                             \
        do {                                                                            \
            _Pragma("unroll")                                                           \
            for (int s2 = 0; s2 < BM / 32; ++s2) {                                      \
                int ca = s2 * 256 + tid;                                                \
                int rw = ca >> 3, kcs = (ca & 7) ^ (rw & 7);                            \
                async_ld16(&lds[(bufi) * BUF + ca * 8],                                 \
                           Abase + (size_t)rw * K + (kt) * 64 + kcs * 8);               \
            }                                                                           \
            _Pragma("unroll")                                                           \
            for (int s2 = 0; s2 < BN / 32; ++s2) {                                      \
                int ca = s2 * 256 + tid;                                                \
                int rw = ca >> 3, kcs = (ca & 7) ^ (rw & 7);                            \
                async_ld16(&lds[(bufi) * BUF + BM * 64 + ca * 8],                       \
                           Bt0 + ((((size_t)(rw >> 6) * KB + (kt)) << 12))              \
                               + (rw & 63) * 64 + kcs * 8);                             \
            }                                                                           \
        } while (0)

    int nk = K >> 6;
    STAGE(0, 0);
    STAGE(1, 1);
    int bufi = 0;
    for (int kt = 0; kt < nk; ++kt) {
        int nxt = bufi + 2; if (nxt >= 3) nxt -= 3;
        if (kt + 2 < nk) {
            STAGE(nxt, kt + 2);
            if constexpr (LPT == 4) WAITVM(8); else WAITVM(12);
        } else if (kt + 1 < nk) {
            if constexpr (LPT == 4) WAITVM(4); else WAITVM(6);
        } else {
            WAITVM(0);
        }
        __builtin_amdgcn_s_barrier();
        __builtin_amdgcn_s_setprio(1);
        #pragma unroll
        for (int kk = 0; kk < 2; ++kk) {
            bf16x8 af[FM], bfr[FN];
            #pragma unroll
            for (int m = 0; m < FM; ++m) {
                int row = wr * WM + m * 16 + l16;
                int csw = (kk * 4 + lg) ^ sw;
                af[m] = *(const bf16x8*)&lds[bufi * BUF + row * 64 + csw * 8];
            }
            #pragma unroll
            for (int n = 0; n < FN; ++n) {
                int row = wc * WN + n * 16 + l16;
                int csw = (kk * 4 + lg) ^ sw;
                bfr[n] = *(const bf16x8*)&lds[bufi * BUF + BM * 64 + row * 64 + csw * 8];
            }
            #pragma unroll
            for (int m = 0; m < FM; ++m)
                #pragma unroll
                for (int n = 0; n < FN; ++n)
                    acc[m][n] = __builtin_amdgcn_mfma_f32_16x16x32_bf16(af[m], bfr[n], acc[m][n], 0, 0, 0);
        }
        __builtin_amdgcn_s_setprio(0);
        __builtin_amdgcn_s_barrier();
        ++bufi; if (bufi >= 3) bufi = 0;
    }
    #undef STAGE

    int r0 = bm0 + wr * WM, c0 = bn0 + wc * WN;
    #pragma unroll
    for (int m = 0; m < FM; ++m) {
        #pragma unroll
        for (int n = 0; n < FN; ++n) {
            int cc = c0 + n * 16 + l16;
            float bcol = bias[cc];
            #pragma unroll
            for (int r = 0; r < 4; ++r) {
                int row = r0 + m * 16 + lg * 4 + r;
                float v = acc[m][n][r] + bcol;
                if (EPI == 0) {
                    ((ushort_t*)outv)[(size_t)row * N + cc] = f2bf(v);
                } else if (EPI == 1) {
                    int p0 = tok[row * 3 + 1], p1 = tok[row * 3 + 2];
                    v += emb_h[p0 * DMODEL + cc] + emb_w[p1 * DMODEL + cc];
                    ((float*)outv)[(size_t)row * N + cc] = v;
                } else if (EPI == 2) {
                    float* op = (float*)outv + (size_t)row * N + cc;
                    *op = *op + v;
                } else {
                    ((ushort_t*)outv)[(size_t)row * N + cc] = f2bf(gelu_exact(v));
                }
            }
        }
    }
}

// ---------------------------------------------------------------- sparse local attention (list-driven)
__global__ __launch_bounds__(256)
void attn_kernel(const ushort_t* __restrict__ qkv, const short* __restrict__ nbr,
                 const int* __restrict__ nbr_cnt, ushort_t* __restrict__ o_out) {
    int tid = threadIdx.x;
    int u = tid >> 2, part = tid & 3;
    int q = blockIdx.x * 16 + (u & 15);
    int h = blockIdx.y * 4 + (u >> 4);
    int b = blockIdx.z;
    int m = b * SEQ + q;
    ushort_t* op = o_out + (size_t)m * DMODEL + h * DHEAD + part * 16;
    int cnt = nbr_cnt[m];
    if (cnt == 0) {
        uint4 z = {0u, 0u, 0u, 0u};
        ((uint4*)op)[0] = z;
        ((uint4*)op)[1] = z;
        return;
    }
    const short* lst = nbr + (size_t)m * 28;
    const ushort_t* qp = qkv + (size_t)m * (3 * DMODEL) + h * DHEAD + part * 16;
    float qv[16], ov[16];
    {
        uint4 u0 = ((const uint4*)qp)[0];
        uint4 u1 = ((const uint4*)qp)[1];
        qv[0] = bf2f(u0.x & 0xffff) * 0.125f; qv[1] = bf2f(u0.x >> 16) * 0.125f;
        qv[2] = bf2f(u0.y & 0xffff) * 0.125f; qv[3] = bf2f(u0.y >> 16) * 0.125f;
        qv[4] = bf2f(u0.z & 0xffff) * 0.125f; qv[5] = bf2f(u0.z >> 16) * 0.125f;
        qv[6] = bf2f(u0.w & 0xffff) * 0.125f; qv[7] = bf2f(u0.w >> 16) * 0.125f;
        qv[8]  = bf2f(u1.x & 0xffff) * 0.125f; qv[9]  = bf2f(u1.x >> 16) * 0.125f;
        qv[10] = bf2f(u1.y & 0xffff) * 0.125f; qv[11] = bf2f(u1.y >> 16) * 0.125f;
        qv[12] = bf2f(u1.z & 0xffff) * 0.125f; qv[13] = bf2f(u1.z >> 16) * 0.125f;
        qv[14] = bf2f(u1.w & 0xffff) * 0.125f; qv[15] = bf2f(u1.w >> 16) * 0.125f;
    }
    #pragma unroll
    for (int i = 0; i < 16; ++i) ov[i] = 0.f;
    float mx = -1e30f, den = 0.f;
    for (int it = 0; it < cnt; ++it) {
        int km = b * SEQ + (int)lst[it];
        const ushort_t* kp = qkv + (size_t)km * (3 * DMODEL) + DMODEL + h * DHEAD + part * 16;
        float dot;
        {
            uint4 u0 = ((const uint4*)kp)[0];
            uint4 u1 = ((const uint4*)kp)[1];
            dot = qv[0] * bf2f(u0.x & 0xffff);
            dot = fmaf(qv[1], bf2f(u0.x >> 16), dot);
            dot = fmaf(qv[2], bf2f(u0.y & 0xffff), dot);
            dot = fmaf(qv[3], bf2f(u0.y >> 16), dot);
            dot = fmaf(qv[4], bf2f(u0.z & 0xffff), dot);
            dot = fmaf(qv[5], bf2f(u0.z >> 16), dot);
            dot = fmaf(qv[6], bf2f(u0.w & 0xffff), dot);
            dot = fmaf(qv[7], bf2f(u0.w >> 16), dot);
            dot = fmaf(qv[8],  bf2f(u1.x & 0xffff), dot);
            dot = fmaf(qv[9],  bf2f(u1.x >> 16), dot);
            dot = fmaf(qv[10], bf2f(u1.y & 0xffff), dot);
            dot = fmaf(qv[11], bf2f(u1.y >> 16), dot);
            dot = fmaf(qv[12], bf2f(u1.z & 0xffff), dot);
            dot = fmaf(qv[13], bf2f(u1.z >> 16), dot);
            dot = fmaf(qv[14], bf2f(u1.w & 0xffff), dot);
            dot = fmaf(qv[15], bf2f(u1.w >> 16), dot);
        }
        dot += __shfl_xor(dot, 1);
        dot += __shfl_xor(dot, 2);
        float sc = dot;
        float nm = fmaxf(mx, sc);
        float c1 = expf(mx - nm);
        float c2 = expf(sc - nm);
        den = den * c1 + c2;
        const ushort_t* vp = qkv + (size_t)km * (3 * DMODEL) + 2 * DMODEL + h * DHEAD + part * 16;
        {
            uint4 u0 = ((const uint4*)vp)[0];
            uint4 u1 = ((const uint4*)vp)[1];
            ov[0] = ov[0] * c1 + c2 * bf2f(u0.x & 0xffff);
            ov[1] = ov[1] * c1 + c2 * bf2f(u0.x >> 16);
            ov[2] = ov[2] * c1 + c2 * bf2f(u0.y & 0xffff);
            ov[3] = ov[3] * c1 + c2 * bf2f(u0.y >> 16);
            ov[4] = ov[4] * c1 + c2 * bf2f(u0.z & 0xffff);
            ov[5] = ov[5] * c1 + c2 * bf2f(u0.z >> 16);
            ov[6] = ov[6] * c1 + c2 * bf2f(u0.w & 0xffff);
            ov[7] = ov[7] * c1 + c2 * bf2f(u0.w >> 16);
            ov[8]  = ov[8]  * c1 + c2 * bf2f(u1.x & 0xffff);
            ov[9]  = ov[9]  * c1 + c2 * bf2f(u1.x >> 16);
            ov[10] = ov[10] * c1 + c2 * bf2f(u1.y & 0xffff);
            ov[11] = ov[11] * c1 + c2 * bf2f(u1.y >> 16);
            ov[12] = ov[12] * c1 + c2 * bf2f(u1.z & 0xffff);
            ov[13] = ov[13] * c1 + c2 * bf2f(u1.z >> 16);
            ov[14] = ov[14] * c1 + c2 * bf2f(u1.w & 0xffff);
            ov[15] = ov[15] * c1 + c2 * bf2f(u1.w >> 16);
        }
        mx = nm;
    }
    float inv = 1.f / den;
    uint4 o0, o1;
    o0.x = (uint_t)f2bf(ov[0] * inv) | ((uint_t)f2bf(ov[1] * inv) << 16);
    o0.y = (uint_t)f2bf(ov[2] * inv) | ((uint_t)f2bf(ov[3] * inv) << 16);
    o0.z = (uint_t)f2bf(ov[4] * inv) | ((uint_t)f2bf(ov[5] * inv) << 16);
    o0.w = (uint_t)f2bf(ov[6] * inv) | ((uint_t)f2bf(ov[7] * inv) << 16);
    o1.x = (uint_t)f2bf(ov[8]  * inv) | ((uint_t)f2bf(ov[9]  * inv) << 16);
    o1.y = (uint_t)f2bf(ov[10] * inv) | ((uint_t)f2bf(ov[11] * inv) << 16);
    o1.z = (uint_t)f2bf(ov[12] * inv) | ((uint_t)f2bf(ov[13] * inv) << 16);
    o1.w = (uint_t)f2bf(ov[14] * inv) | ((uint_t)f2bf(ov[15] * inv) << 16);
    ((uint4*)op)[0] = o0;
    ((uint4*)op)[1] = o1;
}

// ---------------------------------------------------------------- launch
extern "C" void kernel_launch(void* const* d_in, const int* in_sizes, int n_in,
                              void* d_out, int out_size, void* d_ws, size_t ws_size,
                              hipStream_t stream) {
    const float* x_in      = (const float*)d_in[0];
    const int*   t         = (const int*)d_in[1];
    const int*   tok       = (const int*)d_in[2];
    const float* proj_in_w = (const float*)d_in[3];
    const float* proj_in_b = (const float*)d_in[4];
    const float* h_emb     = (const float*)d_in[5];
    const float* w_emb     = (const float*)d_in[6];
    const float* adaln1_w  = (const float*)d_in[7];
    const float* adaln1_b  = (const float*)d_in[8];
    const float* ln1_g     = (const float*)d_in[9];
    const float* ln1_b     = (const float*)d_in[10];
    const float* qkv_w     = (const float*)d_in[11];
    const float* qkv_b     = (const float*)d_in[12];
    const float* o_w       = (const float*)d_in[13];
    const float* o_b       = (const float*)d_in[14];
    const float* adaln2_w  = (const float*)d_in[15];
    const float* adaln2_b  = (const float*)d_in[16];
    const float* ln2_g     = (const float*)d_in[17];
    const float* ln2_b     = (const float*)d_in[18];
    const float* fc1_w     = (const float*)d_in[19];
    const float* fc1_b     = (const float*)d_in[20];
    const float* fc2_w     = (const float*)d_in[21];
    const float* fc2_b     = (const float*)d_in[22];
    const float* nout_w    = (const float*)d_in[23];
    const float* nout_b    = (const float*)d_in[24];
    const float* nout_g    = (const float*)d_in[25];
    const float* nout_beta = (const float*)d_in[26];

    const int M = BATCH * SEQ;   // 4096

    float* stemb   = (float*)d_ws;
    float* e_all   = stemb + BATCH * DMODEL;
    float* partial = e_all + 21 * BATCH * 2 * DMODEL;
    int*   nbr_cnt = (int*)(partial + 21 * 8 * 4 * 2 * DMODEL);
    short* nbr     = (short*)(nbr_cnt + M);
    ushort_t* h_bf   = (ushort_t*)(nbr + (size_t)M * 28);
    ushort_t* qkv_bf = h_bf + (size_t)M * DMODEL;
    ushort_t* hid_bf = qkv_bf + (size_t)M * 3 * DMODEL;
    ushort_t* projT  = hid_bf + (size_t)M * HIDDEN;
    ushort_t* qkvT_a = projT + (size_t)DMODEL * DMODEL;                 // 10 layers
    ushort_t* oT_a   = qkvT_a + (size_t)NLAYER * 3 * DMODEL * DMODEL;
    ushort_t* fc1T_a = oT_a + (size_t)NLAYER * DMODEL * DMODEL;
    ushort_t* fc2T_a = fc1T_a + (size_t)NLAYER * DMODEL * HIDDEN;
    float* x = (float*)d_out;

    temb_silu_kernel<<<BATCH, 384, 0, stream>>>(t, stemb);
    prep_all_kernel<<<PREP_GRID, 256, 0, stream>>>(
        qkv_w, o_w, fc1_w, fc2_w, qkvT_a, oT_a, fc1T_a, fc2T_a,
        proj_in_w, projT, x_in, h_bf, stemb, adaln1_w, adaln2_w, nout_w, partial,
        tok, nbr, nbr_cnt);
    adaln_reduce_kernel<<<dim3(6, 2 * NLAYER + 1), 256, 0, stream>>>(
        partial, adaln1_b, adaln2_b, nout_b, e_all);

    // proj_in: v3 64x64, 768 blocks
    gemm_bf16<64, 64, 1, 3><<<(DMODEL / 64) * (M / 64), 256, 0, stream>>>(
        h_bf, projT, proj_in_b, x, h_emb, w_emb, tok, M, DMODEL, DMODEL);

    for (int i = 0; i < NLAYER; ++i) {
        ln_adaln_kernel<1><<<M / 4, 256, 0, stream>>>(
            x, h_bf, ln1_g + i * DMODEL, ln1_b + i * DMODEL,
            e_all + (size_t)(2 * i) * BATCH * 2 * DMODEL);
        // qkv: 128x128 replica, 576 blocks
        gemm_bf16_big<0><<<(3 * DMODEL / 128) * (M / 128), 256, 0, stream>>>(
            h_bf, qkvT_a + (size_t)i * 3 * DMODEL * DMODEL, qkv_b + i * 3 * DMODEL,
            qkv_bf, M, 3 * DMODEL, DMODEL);
        attn_kernel<<<dim3(SEQ / 16, NHEAD / 4, BATCH), 256, 0, stream>>>(qkv_bf, nbr, nbr_cnt, h_bf);
        // o-proj: v3 64x64, 768 blocks (residual)
        gemm_bf16<64, 64, 2, 3><<<(DMODEL / 64) * (M / 64), 256, 0, stream>>>(
            h_bf, oT_a + (size_t)i * DMODEL * DMODEL, o_b + i * DMODEL,
            x, nullptr, nullptr, nullptr, M, DMODEL, DMODEL);
        ln_adaln_kernel<1><<<M / 4, 256, 0, stream>>>(
            x, h_bf, ln2_g + i * DMODEL, ln2_b + i * DMODEL,
            e_all + (size_t)(2 * i + 1) * BATCH * 2 * DMODEL);
        // fc1: 128x128 replica + gelu, 768 blocks
        gemm_bf16_big<3><<<(HIDDEN / 128) * (M / 128), 256, 0, stream>>>(
            h_bf, fc1T_a + (size_t)i * DMODEL * HIDDEN, fc1_b + i * HIDDEN,
            hid_bf, M, HIDDEN, DMODEL);
        // fc2: v3 pipelined 128x64, 384 blocks (K=3072: 48-step pipeline)
        gemm_bf16<128, 64, 2, 2><<<(DMODEL / 64) * (M / 128), 256, 0, stream>>>(
            hid_bf, fc2T_a + (size_t)i * DMODEL * HIDDEN, fc2_b + i * DMODEL,
            x, nullptr, nullptr, nullptr, M, DMODEL, HIDDEN);
    }

    ln_adaln_kernel<0><<<M / 4, 256, 0, stream>>>(
        x, x, nout_g, nout_beta, e_all + (size_t)(2 * NLAYER) * BATCH * 2 * DMODEL);
}